// Round 6
// baseline (385.472 us; speedup 1.0000x reference)
//
#include <hip/hip_runtime.h>

typedef __attribute__((ext_vector_type(8))) __bf16 bf16x8;
typedef __attribute__((ext_vector_type(4))) __bf16 bf16x4;
typedef __attribute__((ext_vector_type(16))) float f32x16;
typedef __attribute__((ext_vector_type(4))) float f32x4;

#define HH 192
#define WW 192
#define HW 36864
#define HW1 36100

#define COLSTRIDE 144             // bytes per staged col: 64 bf16 = 128B + 16B pad
#define RP66 (66 * COLSTRIDE)     // 9504
#define GDNPITCH 144
#define TREG 8704                 // per-wave transpose region: 32 px x 68 floats x 4B
#define SMEM_BYTES (6 * RP66)     // 57024

__device__ inline f32x16 mfma32(bf16x8 a, bf16x8 b, f32x16 c) {
  return __builtin_amdgcn_mfma_f32_32x32x16_bf16(a, b, c, 0, 0, 0);
}

__device__ inline f32x16 zero16() {
  f32x16 z;
#pragma unroll
  for (int e = 0; e < 16; ++e) z[e] = 0.f;
  return z;
}

// ---------------- weight prep: MFMA A-fragment layouts ----------------
__global__ __launch_bounds__(256) void prep_weights(
    const float* __restrict__ wp, const float* __restrict__ bp,
    const float* __restrict__ wdc, const float* __restrict__ wcat,
    const float* __restrict__ w1, const float* __restrict__ w2,
    const float* __restrict__ gamma,
    __bf16* __restrict__ wpA, __bf16* __restrict__ wdcA,
    __bf16* __restrict__ wcatA, __bf16* __restrict__ w1A,
    __bf16* __restrict__ w2A, __bf16* __restrict__ gA,
    float* __restrict__ bpad) {
  int i = blockIdx.x * 256 + threadIdx.x;
  if (i < 18432) {
    int j = i & 7, lane = (i >> 3) & 63, kc = (i >> 9) & 3, n = i >> 11;
    int o = lane & 31, c = kc * 16 + ((lane >> 5) << 3) + j;
    wpA[i] = (o < 18) ? (__bf16)wp[(o * 64 + c) * 9 + n] : (__bf16)0.f;
    return;
  }
  i -= 18432;
  if (i < 36864) {
    int j = i & 7, lane = (i >> 3) & 63, ot = (i >> 9) & 1, kc = (i >> 10) & 3, n = i >> 12;
    int o = ot * 32 + (lane & 31), c = kc * 16 + ((lane >> 5) << 3) + j;
    wdcA[i] = (__bf16)wdc[(o * 64 + c) * 9 + n];
    return;
  }
  i -= 36864;
  if (i < 73728) {
    int d = i, j = d & 7; d >>= 3; int lane = d & 63; d >>= 6; int ot = d & 1; d >>= 1;
    int kc = d & 7; int n = d >> 3;
    int o = ot * 32 + (lane & 31), c = kc * 16 + ((lane >> 5) << 3) + j;
    wcatA[i] = (__bf16)wcat[(o * 128 + c) * 9 + n];
    return;
  }
  i -= 73728;
  if (i < 110592) {
    int l = i / 36864, di = i % 36864, d = di;
    int j = d & 7; d >>= 3; int lane = d & 63; d >>= 6; int ot = d & 1; d >>= 1;
    int kc = d & 3; int n = d >> 2;
    int o = ot * 32 + (lane & 31), c = kc * 16 + ((lane >> 5) << 3) + j;
    w1A[l * 36864 + di] = (__bf16)w1[l * 36864 + (o * 64 + c) * 9 + n];
    return;
  }
  i -= 110592;
  if (i < 110592) {
    int l = i / 36864, di = i % 36864, d = di;
    int j = d & 7; d >>= 3; int lane = d & 63; d >>= 6; int ot = d & 1; d >>= 1;
    int kc = d & 3; int n = d >> 2;
    int o = ot * 32 + (lane & 31), c = kc * 16 + ((lane >> 5) << 3) + j;
    w2A[l * 36864 + di] = (__bf16)w2[l * 36864 + (o * 64 + c) * 9 + n];
    return;
  }
  i -= 110592;
  if (i < 12288) {
    int l = i / 4096, di = i % 4096, d = di;
    int j = d & 7; d >>= 3; int lane = d & 63; d >>= 6; int ot = d & 1; d >>= 1;
    int kc = d & 3;
    int o = ot * 32 + (lane & 31), c = kc * 16 + ((lane >> 5) << 3) + j;
    gA[l * 4096 + di] = (__bf16)gamma[l * 4096 + o * 64 + c];
    return;
  }
  i -= 12288;
  if (i < 20) bpad[i] = (i < 18) ? bp[i] : 0.f;
}

// ---------------- NCHW fp32 -> NHWC bf16 transpose (f_r and m_t) ----------------
__global__ __launch_bounds__(256) void to_nhwc_bf16(
    const float* __restrict__ fr, const float* __restrict__ mt,
    __bf16* __restrict__ frn, __bf16* __restrict__ mtn) {
  __shared__ __align__(16) __bf16 tile[64 * 72];
  int tensor = blockIdx.x / 1152, rem = blockIdx.x % 1152;
  int b = rem / 576, p0 = (rem % 576) * 64;
  const float* src = (tensor ? mt : fr) + (size_t)b * 64 * HW;
  __bf16* dst = (tensor ? mtn : frn) + (size_t)b * HW * 64;
  int tid = threadIdx.x, c = tid >> 2, q0 = (tid & 3) * 16;
  const float* sp = src + (size_t)c * HW + p0 + q0;
#pragma unroll
  for (int qq = 0; qq < 4; ++qq) {
    f32x4 v = *(const f32x4*)(sp + qq * 4);
#pragma unroll
    for (int e = 0; e < 4; ++e) tile[(q0 + qq * 4 + e) * 72 + c] = (__bf16)v[e];
  }
  __syncthreads();
  int px = tid >> 2, c0 = (tid & 3) * 16;
  bf16x8 a = *(const bf16x8*)(&tile[px * 72 + c0]);
  bf16x8 b8 = *(const bf16x8*)(&tile[px * 72 + c0 + 8]);
  __bf16* dp = dst + (size_t)(p0 + px) * 64 + c0;
  *(bf16x8*)dp = a;
  *(bf16x8*)(dp + 8) = b8;
}

// ---------------- batched staging: load-all -> write-all ----------------
template <int ROWS, int COLS>
__device__ inline void stageB_f32(const float* __restrict__ src,
                                  int srcH, int srcW, int row0, int col0,
                                  unsigned char* lds) {
  constexpr int TOT = ROWS * COLS * 16;
  constexpr int TRIPS = (TOT + 255) / 256;
  f32x4 vals[TRIPS];
  int offs[TRIPS];
#pragma unroll
  for (int t = 0; t < TRIPS; ++t) {
    int i = threadIdx.x + t * 256;
    bool ok = (i < TOT);
    int r = i / (COLS * 16), rem = i - r * (COLS * 16), j = rem >> 4, q = rem & 15;
    int gr = row0 + r, gc = col0 + j;
    bool inb = ok && gr >= 0 && gr < srcH && gc >= 0 && gc < srcW;
    f32x4 z = {0.f, 0.f, 0.f, 0.f};
    vals[t] = z;
    if (inb) vals[t] = *(const f32x4*)(src + ((size_t)gr * srcW + gc) * 64 + q * 4);
    offs[t] = ok ? (r * (COLS * COLSTRIDE) + j * COLSTRIDE + q * 8) : -1;
  }
#pragma unroll
  for (int t = 0; t < TRIPS; ++t) {
    if (offs[t] >= 0) {
      bf16x4 o;
#pragma unroll
      for (int e = 0; e < 4; ++e) o[e] = (__bf16)vals[t][e];
      *(bf16x4*)(lds + offs[t]) = o;
    }
  }
}

template <int ROWS, int COLS, int TRIPS>
__device__ inline void stage_load_bf16(const __bf16* __restrict__ src,
                                       int srcH, int srcW, int row0, int col0,
                                       bf16x8 vals[TRIPS], int offs[TRIPS]) {
  constexpr int TOT = ROWS * COLS * 8;
#pragma unroll
  for (int t = 0; t < TRIPS; ++t) {
    int i = threadIdx.x + t * 256;
    bool ok = (i < TOT);
    int r = i / (COLS * 8), rem = i - r * (COLS * 8), j = rem >> 3, u = rem & 7;
    int gr = row0 + r, gc = col0 + j;
    bool inb = ok && gr >= 0 && gr < srcH && gc >= 0 && gc < srcW;
    bf16x8 z;
#pragma unroll
    for (int e = 0; e < 8; ++e) z[e] = (__bf16)0.f;
    vals[t] = z;
    if (inb) vals[t] = *(const bf16x8*)(src + ((size_t)gr * srcW + gc) * 64 + u * 8);
    offs[t] = ok ? (r * (COLS * COLSTRIDE) + j * COLSTRIDE + u * 16) : -1;
  }
}

template <int TRIPS>
__device__ inline void stage_write_bf16(const bf16x8 vals[TRIPS], const int offs[TRIPS],
                                        unsigned char* lds) {
#pragma unroll
  for (int t = 0; t < TRIPS; ++t)
    if (offs[t] >= 0) *(bf16x8*)(lds + offs[t]) = vals[t];
}

template <int ROWS, int COLS>
__device__ inline void stageB_bf16(const __bf16* __restrict__ src,
                                   int srcH, int srcW, int row0, int col0,
                                   unsigned char* lds) {
  constexpr int TRIPS = (ROWS * COLS * 8 + 255) / 256;
  bf16x8 vals[TRIPS];
  int offs[TRIPS];
  stage_load_bf16<ROWS, COLS, TRIPS>(src, srcH, srcW, row0, col0, vals, offs);
  stage_write_bf16<TRIPS>(vals, offs, lds);
}

// ---------------- A-fragment preload + pipelined K-loop (R3 64px wave tile) ----------------
template <int KC, int KOFFA>
__device__ inline void preloadA8(const __bf16* __restrict__ wA, bf16x8 a0[8]) {
  const __bf16* aB = wA + (threadIdx.x & 63) * 8;
#pragma unroll
  for (int u = 0; u < 8; ++u)
    a0[u] = *(const bf16x8*)(aB + ((KOFFA + (u >> 1)) * 2 + (u & 1)) * 512);
}

template <int KC, int KOFFA, int RP>
__device__ inline void kloopP(const __bf16* __restrict__ wA,
                              const unsigned char* __restrict__ bB,
                              f32x16 acc[2][2], const bf16x8 a0[8]) {
  const int lane = threadIdx.x & 63;
  const __bf16* aB = wA + lane * 8;
  bf16x8 cur[8], nxt[8];
#pragma unroll
  for (int u = 0; u < 8; ++u) cur[u] = a0[u];
#pragma unroll
  for (int n = 0; n < 9; ++n) {
    if (n < 8) {
#pragma unroll
      for (int u = 0; u < 8; ++u)
        nxt[u] = *(const bf16x8*)(aB +
                   (((n + 1) * KC + KOFFA + (u >> 1)) * 2 + (u & 1)) * 512);
    }
    const int kh = n / 3, kw = n % 3;
#pragma unroll
    for (int kc = 0; kc < 4; ++kc) {
      const unsigned char* bp = bB + kh * RP + kw * COLSTRIDE + kc * 32;
      bf16x8 b0 = *(const bf16x8*)(bp);
      bf16x8 b1 = *(const bf16x8*)(bp + 32 * COLSTRIDE);
      acc[0][0] = mfma32(cur[kc * 2 + 0], b0, acc[0][0]);
      acc[0][1] = mfma32(cur[kc * 2 + 0], b1, acc[0][1]);
      acc[1][0] = mfma32(cur[kc * 2 + 1], b0, acc[1][0]);
      acc[1][1] = mfma32(cur[kc * 2 + 1], b1, acc[1][1]);
    }
#pragma unroll
    for (int u = 0; u < 8; ++u) cur[u] = nxt[u];
  }
}

// ---------------- epilogue helpers ----------------
__device__ inline void acchalf_to_lds(const f32x16 acc[2][2], int pt, unsigned char* reg) {
  int lane = threadIdx.x & 63;
  int colb = lane & 31, half = lane >> 5;
#pragma unroll
  for (int ot = 0; ot < 2; ++ot)
#pragma unroll
    for (int g = 0; g < 4; ++g) {
      int o = ot * 32 + half * 4 + g * 8;
      f32x4 v;
      v[0] = acc[ot][pt][g * 4 + 0]; v[1] = acc[ot][pt][g * 4 + 1];
      v[2] = acc[ot][pt][g * 4 + 2]; v[3] = acc[ot][pt][g * 4 + 3];
      *(f32x4*)(reg + (colb * 68 + o) * 4) = v;
    }
}

__device__ inline void read_half(const unsigned char* reg, f32x4 v[8]) {
  int lane = threadIdx.x & 63;
  int col = lane & 31, ch = (lane >> 5) * 32;
#pragma unroll
  for (int q = 0; q < 8; ++q)
    v[q] = *(const f32x4*)(reg + (col * 68 + ch + q * 4) * 4);
}

__device__ inline void acc32_to_lds(const f32x16 acc[2], unsigned char* reg) {
  int lane = threadIdx.x & 63;
  int colb = lane & 31, half = lane >> 5;
#pragma unroll
  for (int ot = 0; ot < 2; ++ot)
#pragma unroll
    for (int g = 0; g < 4; ++g) {
      int o = ot * 32 + half * 4 + g * 8;
      f32x4 v;
      v[0] = acc[ot][g * 4 + 0]; v[1] = acc[ot][g * 4 + 1];
      v[2] = acc[ot][g * 4 + 2]; v[3] = acc[ot][g * 4 + 3];
      *(f32x4*)(reg + (colb * 68 + o) * 4) = v;
    }
}

// ---------------- pconv MFMA: m_t (NHWC bf16) -> off20 [pix][20] fp32 ----------------
__global__ __launch_bounds__(256, 1) void pconv_mfma(
    const __bf16* __restrict__ mtn, const __bf16* __restrict__ wpA,
    const float* __restrict__ bpad, float* __restrict__ off20) {
  __shared__ __align__(16) unsigned char smem[SMEM_BYTES];
  int b = blockIdx.x / 144, r = blockIdx.x % 144, rt = r / 3, ct = r % 3;
  int h0 = rt * 4, w0 = ct * 64;
  int wid = threadIdx.x >> 6, lane = threadIdx.x & 63;
  int colb = lane & 31, half = lane >> 5, kh8 = half << 3;
  stageB_bf16<6, 66>(mtn + (size_t)b * HW * 64, 192, 192, h0 - 1, w0 - 1, smem);
  // preload tap-0 A (4 frags) before barrier
  const __bf16* aB = wpA + lane * 8;
  bf16x8 pcur[4], pnxt[4];
#pragma unroll
  for (int kc = 0; kc < 4; ++kc) pcur[kc] = *(const bf16x8*)(aB + kc * 512);
  __syncthreads();
  f32x16 acc[2];
  acc[0] = zero16(); acc[1] = zero16();
  {
    const unsigned char* bB = smem + wid * RP66 + colb * COLSTRIDE + kh8 * 2;
#pragma unroll
    for (int n = 0; n < 9; ++n) {
      if (n < 8) {
#pragma unroll
        for (int kc = 0; kc < 4; ++kc)
          pnxt[kc] = *(const bf16x8*)(aB + ((n + 1) * 4 + kc) * 512);
      }
      const int kh = n / 3, kw = n % 3;
#pragma unroll
      for (int kc = 0; kc < 4; ++kc) {
        const unsigned char* bp = bB + kh * RP66 + kw * COLSTRIDE + kc * 32;
        bf16x8 b0 = *(const bf16x8*)(bp);
        bf16x8 b1 = *(const bf16x8*)(bp + 32 * COLSTRIDE);
        acc[0] = mfma32(pcur[kc], b0, acc[0]);
        acc[1] = mfma32(pcur[kc], b1, acc[1]);
      }
#pragma unroll
      for (int kc = 0; kc < 4; ++kc) pcur[kc] = pnxt[kc];
    }
  }
  __syncthreads();
  unsigned char* reg = smem + wid * 9216;
#pragma unroll
  for (int pt = 0; pt < 2; ++pt)
#pragma unroll
    for (int g = 0; g < 4; ++g) {
      int o = half * 4 + g * 8;
      f32x4 v;
      v[0] = acc[pt][g * 4 + 0]; v[1] = acc[pt][g * 4 + 1];
      v[2] = acc[pt][g * 4 + 2]; v[3] = acc[pt][g * 4 + 3];
      *(f32x4*)(reg + ((pt * 32 + colb) * 36 + o) * 4) = v;
    }
  __builtin_amdgcn_s_waitcnt(0);
  size_t pix = (size_t)b * HW + (size_t)(h0 + wid) * 192 + w0 + lane;
#pragma unroll
  for (int q = 0; q < 5; ++q) {
    f32x4 v = *(const f32x4*)(reg + (lane * 36 + q * 4) * 4);
    v += *(const f32x4*)(bpad + q * 4);
    *(f32x4*)(off20 + pix * 20 + q * 4) = v;
  }
}

// ---------------- deformable conv (R3 version, unchanged) ----------------
__global__ __launch_bounds__(128, 2) void deform_mfma(
    const __bf16* __restrict__ frn, const float* __restrict__ off20,
    const __bf16* __restrict__ wdcA, float* __restrict__ xlow) {
  __shared__ __align__(16) unsigned char smem[2 * 18432];
  int b = blockIdx.x / 576, r = blockIdx.x % 576;
  int h = r / 3, ct = r % 3;
  int w0 = ct * 64;
  int wid = threadIdx.x >> 6, lane = threadIdx.x & 63;
  int wcol0 = w0 + wid * 32;
  unsigned char* wbase = smem + wid * 18432;
  float* goL = (float*)wbase;
  unsigned char* dbuf = wbase + 9216;
  const __bf16* xb = frn + (size_t)b * HW * 64;
  {
    int px = lane & 31, par = lane >> 5;
    int w = wcol0 + px;
    size_t pixl = (size_t)b * HW + (size_t)h * 192 + w;
    const float* ofp = off20 + pixl * 20;
    for (int n = par; n < 9; n += 2) {
      float offr = ofp[n], offc = ofp[9 + n];
      float pr = (float)(h + 1 + n / 3 - 1) + offr;
      float pc = (float)(w + 1 + n % 3 - 1) + offc;
      float prc = fminf(fmaxf(pr, 0.f), 193.f);
      float pcc = fminf(fmaxf(pc, 0.f), 193.f);
      float f0r = floorf(pr), f0c = floorf(pc);
      int qr0 = (int)fminf(fmaxf(f0r, 0.f), 193.f);
      int qc0 = (int)fminf(fmaxf(f0c, 0.f), 193.f);
      int qr1 = (int)fminf(fmaxf(f0r + 1.f, 0.f), 193.f);
      int qc1 = (int)fminf(fmaxf(f0c + 1.f, 0.f), 193.f);
      float dr0 = 1.f + ((float)qr0 - prc);
      float dr1 = 1.f - ((float)qr1 - prc);
      float dc0 = 1.f + ((float)qc0 - pcc);
      float dc1 = 1.f - ((float)qc1 - pcc);
      int o0, o1, o2, o3; float g0, g1, g2, g3;
      { bool v = (qr0 >= 1 && qr0 <= 192 && qc0 >= 1 && qc0 <= 192);
        o0 = min(max(qr0-1,0),191)*WW + min(max(qc0-1,0),191); g0 = v ? dr0*dc0 : 0.f; }
      { bool v = (qr1 >= 1 && qr1 <= 192 && qc1 >= 1 && qc1 <= 192);
        o1 = min(max(qr1-1,0),191)*WW + min(max(qc1-1,0),191); g1 = v ? dr1*dc1 : 0.f; }
      { bool v = (qr0 >= 1 && qr0 <= 192 && qc1 >= 1 && qc1 <= 192);
        o2 = min(max(qr0-1,0),191)*WW + min(max(qc1-1,0),191); g2 = v ? dr0*dc1 : 0.f; }
      { bool v = (qr1 >= 1 && qr1 <= 192 && qc0 >= 1 && qc0 <= 192);
        o3 = min(max(qr1-1,0),191)*WW + min(max(qc0-1,0),191); g3 = v ? dr1*dc0 : 0.f; }
      float* dst = goL + ((size_t)n * 32 + px) * 8;
      dst[0] = g0; dst[1] = g1; dst[2] = g2; dst[3] = g3;
      int* di = (int*)(dst + 4);
      di[0] = o0; di[1] = o1; di[2] = o2; di[3] = o3;
    }
  }
  f32x16 acc[2];
  acc[0] = zero16(); acc[1] = zero16();
  const __bf16* aB = wdcA + lane * 8;
  const int po = lane >> 3, cg = lane & 7;
  const int m = lane & 31, kh8 = (lane >> 5) << 3;
#pragma unroll
  for (int n = 0; n < 9; ++n) {
    unsigned char* buf = dbuf + (n & 1) * 4608;
#pragma unroll
    for (int i = 0; i < 4; ++i) {
      int px = po * 4 + i;
      const float* gsrc = goL + ((size_t)n * 32 + px) * 8;
      f32x4 g4 = *(const f32x4*)gsrc;
      const int* oi = (const int*)(gsrc + 4);
      bf16x8 c0 = *(const bf16x8*)(xb + (size_t)oi[0] * 64 + cg * 8);
      bf16x8 c1 = *(const bf16x8*)(xb + (size_t)oi[1] * 64 + cg * 8);
      bf16x8 c2 = *(const bf16x8*)(xb + (size_t)oi[2] * 64 + cg * 8);
      bf16x8 c3 = *(const bf16x8*)(xb + (size_t)oi[3] * 64 + cg * 8);
      bf16x8 ov;
#pragma unroll
      for (int e = 0; e < 8; ++e) {
        float f = g4[0] * (float)c0[e] + g4[1] * (float)c1[e] +
                  g4[2] * (float)c2[e] + g4[3] * (float)c3[e];
        ov[e] = (__bf16)f;
      }
      *(bf16x8*)(buf + px * COLSTRIDE + cg * 16) = ov;
    }
    const unsigned char* bB = buf + m * COLSTRIDE + kh8 * 2;
#pragma unroll
    for (int kc = 0; kc < 4; ++kc) {
      bf16x8 a0 = *(const bf16x8*)(aB + ((n * 4 + kc) * 2 + 0) * 512);
      bf16x8 a1 = *(const bf16x8*)(aB + ((n * 4 + kc) * 2 + 1) * 512);
      bf16x8 b0 = *(const bf16x8*)(bB + kc * 32);
      acc[0] = mfma32(a0, b0, acc[0]);
      acc[1] = mfma32(a1, b0, acc[1]);
    }
  }
  unsigned char* reg = dbuf;
  acc32_to_lds(acc, reg);
  __builtin_amdgcn_s_waitcnt(0);
  int colb = lane & 31, half = lane >> 5, ch = half * 32;
  float* dp = xlow + ((size_t)b * HW + (size_t)h * 192 + wcol0 + colb) * 64 + ch;
#pragma unroll
  for (int q = 0; q < 8; ++q)
    *(f32x4*)(dp + q * 4) = *(const f32x4*)(reg + (colb * 68 + ch + q * 4) * 4);
}

// ---------------- convcat: R3 tiling + batched stage + pipelined A ----------------
__global__ __launch_bounds__(256, 1) void convcat_mfma(
    const float* __restrict__ xlow, const __bf16* __restrict__ frn,
    const __bf16* __restrict__ wA, const float* __restrict__ bias,
    float* __restrict__ y) {
  __shared__ __align__(16) unsigned char smem[SMEM_BYTES];
  int b = blockIdx.x / 144, r = blockIdx.x % 144, rt = r / 3, ct = r % 3;
  int h0 = rt * 4, w0 = ct * 64;
  int wid = threadIdx.x >> 6, lane = threadIdx.x & 63;
  int m = lane & 31, kh8 = (lane >> 5) << 3;
  const unsigned char* bB = smem + wid * RP66 + m * COLSTRIDE + kh8 * 2;
  f32x16 acc[2][2];
  acc[0][0] = zero16(); acc[0][1] = zero16(); acc[1][0] = zero16(); acc[1][1] = zero16();
  // stage half-1 (xlow f32), issue half-2 loads (frn) + tap0 A into regs pre-barrier
  stageB_f32<6, 66>(xlow + (size_t)b * HW * 64, 192, 192, h0 - 1, w0 - 1, smem);
  bf16x8 v2[13]; int o2[13];
  stage_load_bf16<6, 66, 13>(frn + (size_t)b * HW * 64, 192, 192, h0 - 1, w0 - 1, v2, o2);
  bf16x8 a0[8];
  preloadA8<8, 0>(wA, a0);
  __syncthreads();
  kloopP<8, 0, RP66>(wA, bB, acc, a0);
  __syncthreads();
  stage_write_bf16<13>(v2, o2, smem);
  preloadA8<8, 4>(wA, a0);
  __syncthreads();
  kloopP<8, 4, RP66>(wA, bB, acc, a0);
  __syncthreads();
  unsigned char* reg = smem + wid * TREG;
  float* dsty = y + ((size_t)b * HW + (size_t)(h0 + wid) * 192 + w0) * 64;
  int col = lane & 31, ch = (lane >> 5) * 32;
#pragma unroll
  for (int pt = 0; pt < 2; ++pt) {
    acchalf_to_lds(acc, pt, reg);
    __builtin_amdgcn_s_waitcnt(0);
    f32x4 v[8];
    read_half(reg, v);
    float* dp = dsty + (size_t)(pt * 32 + col) * 64 + ch;
#pragma unroll
    for (int q = 0; q < 8; ++q) {
      f32x4 bv = *(const f32x4*)(bias + ch + q * 4);
      v[q] += bv;
      *(f32x4*)(dp + q * 4) = v[q];
    }
  }
}

// ---------------- conv1 + GDN + CELU: R3 tiling + batched stage + pipelined A ----------------
__global__ __launch_bounds__(256, 1) void conv1gdn_mfma(
    const float* __restrict__ y, const __bf16* __restrict__ w1A,
    const __bf16* __restrict__ gA, const float* __restrict__ beta,
    __bf16* __restrict__ hbuf) {
  __shared__ __align__(16) unsigned char smem[SMEM_BYTES];
  int b = blockIdx.x / 144, r = blockIdx.x % 144, rt = r / 3, ct = r % 3;
  int h0 = rt * 4, w0 = ct * 64;
  int wid = threadIdx.x >> 6, lane = threadIdx.x & 63;
  int colb = lane & 31, half = lane >> 5;
  const int kh8 = half << 3;
  const unsigned char* bB = smem + wid * RP66 + colb * COLSTRIDE + kh8 * 2;
  f32x16 acc[2][2];
  acc[0][0] = zero16(); acc[0][1] = zero16(); acc[1][0] = zero16(); acc[1][1] = zero16();
  stageB_f32<6, 66>(y + (size_t)b * HW * 64, 192, 192, h0, w0, smem);
  bf16x8 a0[8];
  preloadA8<4, 0>(w1A, a0);
  __syncthreads();
  kloopP<4, 0, RP66>(w1A, bB, acc, a0);
  __syncthreads();
#pragma unroll
  for (int ot = 0; ot < 2; ++ot)
#pragma unroll
    for (int pt = 0; pt < 2; ++pt)
#pragma unroll
      for (int g = 0; g < 4; ++g) {
        int o = ot * 32 + half * 4 + g * 8;
        int p = wid * 64 + pt * 32 + colb;
        bf16x4 s;
#pragma unroll
        for (int e = 0; e < 4; ++e) {
          float x = acc[ot][pt][g * 4 + e];
          s[e] = (__bf16)(x * x);
        }
        *(bf16x4*)(smem + p * GDNPITCH + o * 2) = s;
      }
  __syncthreads();
  f32x16 nacc[2][2];
  nacc[0][0] = zero16(); nacc[0][1] = zero16(); nacc[1][0] = zero16(); nacc[1][1] = zero16();
  {
    const __bf16* gaB = gA + lane * 8;
    const unsigned char* gb = smem + (wid * 64 + colb) * GDNPITCH + kh8 * 2;
#pragma unroll
    for (int kc = 0; kc < 4; ++kc) {
      bf16x8 ga0 = *(const bf16x8*)(gaB + (kc * 2 + 0) * 512);
      bf16x8 ga1 = *(const bf16x8*)(gaB + (kc * 2 + 1) * 512);
      bf16x8 b0 = *(const bf16x8*)(gb + kc * 32);
      bf16x8 b1 = *(const bf16x8*)(gb + 32 * GDNPITCH + kc * 32);
      nacc[0][0] = mfma32(ga0, b0, nacc[0][0]);
      nacc[0][1] = mfma32(ga0, b1, nacc[0][1]);
      nacc[1][0] = mfma32(ga1, b0, nacc[1][0]);
      nacc[1][1] = mfma32(ga1, b1, nacc[1][1]);
    }
  }
#pragma unroll
  for (int ot = 0; ot < 2; ++ot)
#pragma unroll
    for (int g = 0; g < 4; ++g) {
      f32x4 bet = *(const f32x4*)(beta + ot * 32 + half * 4 + g * 8);
#pragma unroll
      for (int pt = 0; pt < 2; ++pt)
#pragma unroll
        for (int e = 0; e < 4; ++e) {
          float nv = bet[e] + nacc[ot][pt][g * 4 + e];
          float hv = acc[ot][pt][g * 4 + e] * rsqrtf(nv);
          hv = hv > 0.f ? hv : expf(hv) - 1.f;
          acc[ot][pt][g * 4 + e] = hv;
        }
    }
  __syncthreads();
  unsigned char* reg = smem + wid * TREG;
  int hr = h0 + wid;
  bool rowok = hr < 190;
  int ch = half * 32;
#pragma unroll
  for (int pt = 0; pt < 2; ++pt) {
    acchalf_to_lds(acc, pt, reg);
    __builtin_amdgcn_s_waitcnt(0);
    f32x4 v[8];
    read_half(reg, v);
    int wcol = w0 + pt * 32 + colb;
    if (rowok && wcol < 190) {
      __bf16* dp = hbuf + ((size_t)b * HW1 + (size_t)hr * 190 + wcol) * 64 + ch;
#pragma unroll
      for (int q = 0; q < 8; ++q) {
        bf16x4 o;
#pragma unroll
        for (int e = 0; e < 4; ++e) o[e] = (__bf16)v[q][e];
        *(bf16x4*)(dp + q * 4) = o;
      }
    }
  }
}

// ---------------- conv2 (pad 2) + residual: R3 tiling + batched stage + pipelined A ----------------
template <bool LAST>
__global__ __launch_bounds__(256, 1) void conv2_mfma(
    const __bf16* __restrict__ hbuf, const __bf16* __restrict__ w2A,
    const float* __restrict__ xlow, float* __restrict__ y,
    float* __restrict__ out) {
  __shared__ __align__(16) unsigned char smem[SMEM_BYTES];
  int b = blockIdx.x / 144, r = blockIdx.x % 144, rt = r / 3, ct = r % 3;
  int h0 = rt * 4, w0 = ct * 64;
  int wid = threadIdx.x >> 6, lane = threadIdx.x & 63;
  int m = lane & 31, kh8 = (lane >> 5) << 3;
  const unsigned char* bB = smem + wid * RP66 + m * COLSTRIDE + kh8 * 2;
  f32x16 acc[2][2];
  acc[0][0] = zero16(); acc[0][1] = zero16(); acc[1][0] = zero16(); acc[1][1] = zero16();
  stageB_bf16<6, 66>(hbuf + (size_t)b * HW1 * 64, 190, 190, h0 - 2, w0 - 2, smem);
  bf16x8 a0[8];
  preloadA8<4, 0>(w2A, a0);
  __syncthreads();
  kloopP<4, 0, RP66>(w2A, bB, acc, a0);
  __syncthreads();
  unsigned char* reg = smem + wid * TREG;
  int col = lane & 31, ch = (lane >> 5) * 32;
  size_t pixbase = (size_t)b * HW + (size_t)(h0 + wid) * 192 + w0;
#pragma unroll
  for (int pt = 0; pt < 2; ++pt) {
    acchalf_to_lds(acc, pt, reg);
    __builtin_amdgcn_s_waitcnt(0);
    f32x4 v[8];
    read_half(reg, v);
    size_t pix = pixbase + pt * 32 + col;
    float* yp = y + pix * 64 + ch;
#pragma unroll
    for (int q = 0; q < 8; ++q) v[q] += *(const f32x4*)(yp + q * 4);
    if (!LAST) {
#pragma unroll
      for (int q = 0; q < 8; ++q) *(f32x4*)(yp + q * 4) = v[q];
    } else {
      const float* xp = xlow + pix * 64 + ch;
#pragma unroll
      for (int q = 0; q < 8; ++q) v[q] += *(const f32x4*)(xp + q * 4);
#pragma unroll
      for (int q = 0; q < 8; ++q)
        *(f32x4*)(reg + (col * 68 + ch + q * 4) * 4) = v[q];
      __builtin_amdgcn_s_waitcnt(0);
      int o = lane;
      float* op = out + ((size_t)b * 64 + o) * HW + (size_t)(h0 + wid) * 192 + w0 + pt * 32;
#pragma unroll
      for (int q = 0; q < 8; ++q) {
        f32x4 s;
#pragma unroll
        for (int e = 0; e < 4; ++e)
          s[e] = *(const float*)(reg + ((q * 4 + e) * 68 + o) * 4);
        *(f32x4*)(op + q * 4) = s;
      }
    }
  }
}

extern "C" void kernel_launch(void* const* d_in, const int* in_sizes, int n_in,
                              void* d_out, int out_size, void* d_ws, size_t ws_size,
                              hipStream_t stream) {
  const float* f_r      = (const float*)d_in[0];
  const float* m_t      = (const float*)d_in[1];
  const float* w_pconv  = (const float*)d_in[2];
  const float* b_pconv  = (const float*)d_in[3];
  const float* w_dc     = (const float*)d_in[4];
  const float* w_cat    = (const float*)d_in[5];
  const float* b_cat    = (const float*)d_in[6];
  const float* rb_w1    = (const float*)d_in[7];
  const float* rb_w2    = (const float*)d_in[8];
  const float* rb_beta  = (const float*)d_in[9];
  const float* rb_gamma = (const float*)d_in[10];
  float* out = (float*)d_out;

  float* ws = (float*)d_ws;
  float*  xlow  = ws;                         // [2][HW][64] f32
  float*  ybuf  = xlow + 4718592;             // [2][HW][64] f32
  float*  off20 = ybuf + 4718592;             // [2][HW][20] f32
  __bf16* frn   = (__bf16*)(off20 + 1474560); // [2][HW][64] bf16
  __bf16* mtn   = (__bf16*)(off20 + 1474560 + 2359296);
  __bf16* hbuf  = mtn;                        // mtn dead after pconv
  float*  wbase = off20 + 1474560 + 2359296 + 2359296;
  __bf16* wpA   = (__bf16*)wbase;
  __bf16* wdcA  = (__bf16*)(wbase + 9216);
  __bf16* wcatA = (__bf16*)(wbase + 27648);
  __bf16* w1A   = (__bf16*)(wbase + 64512);
  __bf16* w2A   = (__bf16*)(wbase + 119808);
  __bf16* gA    = (__bf16*)(wbase + 175104);
  float*  bpad  = wbase + 181248;

  prep_weights<<<1417, 256, 0, stream>>>(w_pconv, b_pconv, w_dc, w_cat, rb_w1, rb_w2,
                                         rb_gamma, wpA, wdcA, wcatA, w1A, w2A, gA, bpad);
  to_nhwc_bf16<<<2304, 256, 0, stream>>>(f_r, m_t, frn, mtn);
  pconv_mfma<<<288, 256, 0, stream>>>(mtn, wpA, bpad, off20);
  deform_mfma<<<1152, 128, 0, stream>>>(frn, off20, wdcA, xlow);
  convcat_mfma<<<288, 256, 0, stream>>>(xlow, frn, wcatA, b_cat, ybuf);
  for (int l = 0; l < 3; ++l) {
    conv1gdn_mfma<<<288, 256, 0, stream>>>(ybuf, w1A + l * 36864, gA + l * 4096,
                                           rb_beta + l * 64, hbuf);
    if (l < 2)
      conv2_mfma<false><<<288, 256, 0, stream>>>(hbuf, w2A + l * 36864, xlow, ybuf, out);
    else
      conv2_mfma<true><<<288, 256, 0, stream>>>(hbuf, w2A + l * 36864, xlow, ybuf, out);
  }
}

// Round 7
// 365.588 us; speedup vs baseline: 1.0544x; 1.0544x over previous
//
#include <hip/hip_runtime.h>

typedef __attribute__((ext_vector_type(8))) __bf16 bf16x8;
typedef __attribute__((ext_vector_type(4))) __bf16 bf16x4;
typedef __attribute__((ext_vector_type(16))) float f32x16;
typedef __attribute__((ext_vector_type(4))) float f32x4;

#define HH 192
#define WW 192
#define HW 36864
#define HW1 36100

#define TCS 144                  // bytes per staged col: 64 bf16 = 128B + 16B pad
#define RP66 (66 * TCS)          // pconv staging row pitch
#define RPA (34 * TCS)           // 4896: pad-1 conv tiles (6 rows x 34 cols)
#define RPB (36 * TCS)           // 5184: conv2 pad-2 tiles (8 rows x 36 cols)
#define LDSA (6 * RPA)           // 29376
#define LDSB (8 * RPB)           // 41472
#define GDNPITCH 144
#define TREG 8704                // per-wave transpose region: 32 px x 68 f32

__device__ inline f32x16 mfma32(bf16x8 a, bf16x8 b, f32x16 c) {
  return __builtin_amdgcn_mfma_f32_32x32x16_bf16(a, b, c, 0, 0, 0);
}

__device__ inline f32x16 zero16() {
  f32x16 z;
#pragma unroll
  for (int e = 0; e < 16; ++e) z[e] = 0.f;
  return z;
}

// ---------------- weight prep: MFMA A-fragment layouts ----------------
__global__ __launch_bounds__(256) void prep_weights(
    const float* __restrict__ wp, const float* __restrict__ bp,
    const float* __restrict__ wdc, const float* __restrict__ wcat,
    const float* __restrict__ w1, const float* __restrict__ w2,
    const float* __restrict__ gamma,
    __bf16* __restrict__ wpA, __bf16* __restrict__ wdcA,
    __bf16* __restrict__ wcatA, __bf16* __restrict__ w1A,
    __bf16* __restrict__ w2A, __bf16* __restrict__ gA,
    float* __restrict__ bpad) {
  int i = blockIdx.x * 256 + threadIdx.x;
  if (i < 18432) {
    int j = i & 7, lane = (i >> 3) & 63, kc = (i >> 9) & 3, n = i >> 11;
    int o = lane & 31, c = kc * 16 + ((lane >> 5) << 3) + j;
    wpA[i] = (o < 18) ? (__bf16)wp[(o * 64 + c) * 9 + n] : (__bf16)0.f;
    return;
  }
  i -= 18432;
  if (i < 36864) {
    int j = i & 7, lane = (i >> 3) & 63, ot = (i >> 9) & 1, kc = (i >> 10) & 3, n = i >> 12;
    int o = ot * 32 + (lane & 31), c = kc * 16 + ((lane >> 5) << 3) + j;
    wdcA[i] = (__bf16)wdc[(o * 64 + c) * 9 + n];
    return;
  }
  i -= 36864;
  if (i < 73728) {
    int d = i, j = d & 7; d >>= 3; int lane = d & 63; d >>= 6; int ot = d & 1; d >>= 1;
    int kc = d & 7; int n = d >> 3;
    int o = ot * 32 + (lane & 31), c = kc * 16 + ((lane >> 5) << 3) + j;
    wcatA[i] = (__bf16)wcat[(o * 128 + c) * 9 + n];
    return;
  }
  i -= 73728;
  if (i < 110592) {
    int l = i / 36864, di = i % 36864, d = di;
    int j = d & 7; d >>= 3; int lane = d & 63; d >>= 6; int ot = d & 1; d >>= 1;
    int kc = d & 3; int n = d >> 2;
    int o = ot * 32 + (lane & 31), c = kc * 16 + ((lane >> 5) << 3) + j;
    w1A[l * 36864 + di] = (__bf16)w1[l * 36864 + (o * 64 + c) * 9 + n];
    return;
  }
  i -= 110592;
  if (i < 110592) {
    int l = i / 36864, di = i % 36864, d = di;
    int j = d & 7; d >>= 3; int lane = d & 63; d >>= 6; int ot = d & 1; d >>= 1;
    int kc = d & 3; int n = d >> 2;
    int o = ot * 32 + (lane & 31), c = kc * 16 + ((lane >> 5) << 3) + j;
    w2A[l * 36864 + di] = (__bf16)w2[l * 36864 + (o * 64 + c) * 9 + n];
    return;
  }
  i -= 110592;
  if (i < 12288) {
    int l = i / 4096, di = i % 4096, d = di;
    int j = d & 7; d >>= 3; int lane = d & 63; d >>= 6; int ot = d & 1; d >>= 1;
    int kc = d & 3;
    int o = ot * 32 + (lane & 31), c = kc * 16 + ((lane >> 5) << 3) + j;
    gA[l * 4096 + di] = (__bf16)gamma[l * 4096 + o * 64 + c];
    return;
  }
  i -= 12288;
  if (i < 20) bpad[i] = (i < 18) ? bp[i] : 0.f;
}

// ---------------- NCHW fp32 -> NHWC bf16 transpose (f_r and m_t) ----------------
__global__ __launch_bounds__(256) void to_nhwc_bf16(
    const float* __restrict__ fr, const float* __restrict__ mt,
    __bf16* __restrict__ frn, __bf16* __restrict__ mtn) {
  __shared__ __align__(16) __bf16 tile[64 * 72];
  int tensor = blockIdx.x / 1152, rem = blockIdx.x % 1152;
  int b = rem / 576, p0 = (rem % 576) * 64;
  const float* src = (tensor ? mt : fr) + (size_t)b * 64 * HW;
  __bf16* dst = (tensor ? mtn : frn) + (size_t)b * HW * 64;
  int tid = threadIdx.x, c = tid >> 2, q0 = (tid & 3) * 16;
  const float* sp = src + (size_t)c * HW + p0 + q0;
#pragma unroll
  for (int qq = 0; qq < 4; ++qq) {
    f32x4 v = *(const f32x4*)(sp + qq * 4);
#pragma unroll
    for (int e = 0; e < 4; ++e) tile[(q0 + qq * 4 + e) * 72 + c] = (__bf16)v[e];
  }
  __syncthreads();
  int px = tid >> 2, c0 = (tid & 3) * 16;
  bf16x8 a = *(const bf16x8*)(&tile[px * 72 + c0]);
  bf16x8 b8 = *(const bf16x8*)(&tile[px * 72 + c0 + 8]);
  __bf16* dp = dst + (size_t)(p0 + px) * 64 + c0;
  *(bf16x8*)dp = a;
  *(bf16x8*)(dp + 8) = b8;
}

// ---------------- simple staging loops (low-VGPR, R3-form) ----------------
template <int ROWS, int COLS, int TPB>
__device__ inline void stage_f32T(const float* __restrict__ src,
                                  int srcH, int srcW, int row0, int col0,
                                  unsigned char* lds) {
  for (int i = threadIdx.x; i < ROWS * COLS * 16; i += TPB) {
    int r = i / (COLS * 16), rem = i - r * (COLS * 16), j = rem >> 4, q = rem & 15;
    int gr = row0 + r, gc = col0 + j;
    f32x4 v = {0.f, 0.f, 0.f, 0.f};
    if (gr >= 0 && gr < srcH && gc >= 0 && gc < srcW)
      v = *(const f32x4*)(src + ((size_t)gr * srcW + gc) * 64 + q * 4);
    bf16x4 o;
#pragma unroll
    for (int e = 0; e < 4; ++e) o[e] = (__bf16)v[e];
    *(bf16x4*)(lds + r * (COLS * TCS) + j * TCS + q * 8) = o;
  }
}

template <int ROWS, int COLS, int TPB>
__device__ inline void stage_bf16T(const __bf16* __restrict__ src,
                                   int srcH, int srcW, int row0, int col0,
                                   unsigned char* lds) {
  for (int i = threadIdx.x; i < ROWS * COLS * 8; i += TPB) {
    int r = i / (COLS * 8), rem = i - r * (COLS * 8), j = rem >> 3, u = rem & 7;
    int gr = row0 + r, gc = col0 + j;
    bf16x8 v;
#pragma unroll
    for (int e = 0; e < 8; ++e) v[e] = (__bf16)0.f;
    if (gr >= 0 && gr < srcH && gc >= 0 && gc < srcW)
      v = *(const bf16x8*)(src + ((size_t)gr * srcW + gc) * 64 + u * 8);
    *(bf16x8*)(lds + r * (COLS * TCS) + j * TCS + u * 16) = v;
  }
}

// ---------------- K-loop: wave tile 64o x 64px (2 rows x 32 cols; b1 = +RP) ----------------
template <int KC, int KOFFA, int RP>
__device__ inline void kloopT(const __bf16* __restrict__ wA,
                              const unsigned char* __restrict__ bB,
                              f32x16 acc[2][2]) {
  const int lane = threadIdx.x & 63;
  const __bf16* aB = wA + lane * 8;
#pragma unroll
  for (int n = 0; n < 9; ++n) {
    const int kh = n / 3, kw = n % 3;
#pragma unroll
    for (int kc = 0; kc < 4; ++kc) {
      bf16x8 a0 = *(const bf16x8*)(aB + ((n * KC + KOFFA + kc) * 2 + 0) * 512);
      bf16x8 a1 = *(const bf16x8*)(aB + ((n * KC + KOFFA + kc) * 2 + 1) * 512);
      const unsigned char* bp = bB + kh * RP + kw * TCS + kc * 32;
      bf16x8 b0 = *(const bf16x8*)(bp);
      bf16x8 b1 = *(const bf16x8*)(bp + RP);   // second px-half = next image row
      acc[0][0] = mfma32(a0, b0, acc[0][0]);
      acc[0][1] = mfma32(a0, b1, acc[0][1]);
      acc[1][0] = mfma32(a1, b0, acc[1][0]);
      acc[1][1] = mfma32(a1, b1, acc[1][1]);
    }
  }
}

// ---------------- epilogue helpers ----------------
__device__ inline void acchalf_to_lds(const f32x16 acc[2][2], int pt, unsigned char* reg) {
  int lane = threadIdx.x & 63;
  int colb = lane & 31, half = lane >> 5;
#pragma unroll
  for (int ot = 0; ot < 2; ++ot)
#pragma unroll
    for (int g = 0; g < 4; ++g) {
      int o = ot * 32 + half * 4 + g * 8;
      f32x4 v;
      v[0] = acc[ot][pt][g * 4 + 0]; v[1] = acc[ot][pt][g * 4 + 1];
      v[2] = acc[ot][pt][g * 4 + 2]; v[3] = acc[ot][pt][g * 4 + 3];
      *(f32x4*)(reg + (colb * 68 + o) * 4) = v;
    }
}

__device__ inline void read_half(const unsigned char* reg, f32x4 v[8]) {
  int lane = threadIdx.x & 63;
  int col = lane & 31, ch = (lane >> 5) * 32;
#pragma unroll
  for (int q = 0; q < 8; ++q)
    v[q] = *(const f32x4*)(reg + (col * 68 + ch + q * 4) * 4);
}

__device__ inline void acc32_to_lds(const f32x16 acc[2], unsigned char* reg) {
  int lane = threadIdx.x & 63;
  int colb = lane & 31, half = lane >> 5;
#pragma unroll
  for (int ot = 0; ot < 2; ++ot)
#pragma unroll
    for (int g = 0; g < 4; ++g) {
      int o = ot * 32 + half * 4 + g * 8;
      f32x4 v;
      v[0] = acc[ot][g * 4 + 0]; v[1] = acc[ot][g * 4 + 1];
      v[2] = acc[ot][g * 4 + 2]; v[3] = acc[ot][g * 4 + 3];
      *(f32x4*)(reg + (colb * 68 + o) * 4) = v;
    }
}

// ---------------- pconv MFMA (R5 version, unchanged) ----------------
__global__ __launch_bounds__(256, 1) void pconv_mfma(
    const __bf16* __restrict__ mtn, const __bf16* __restrict__ wpA,
    const float* __restrict__ bpad, float* __restrict__ off20) {
  __shared__ __align__(16) unsigned char smem[6 * RP66];
  int b = blockIdx.x / 144, r = blockIdx.x % 144, rt = r / 3, ct = r % 3;
  int h0 = rt * 4, w0 = ct * 64;
  int wid = threadIdx.x >> 6, lane = threadIdx.x & 63;
  int colb = lane & 31, half = lane >> 5, kh8 = half << 3;
  stage_bf16T<6, 66, 256>(mtn + (size_t)b * HW * 64, 192, 192, h0 - 1, w0 - 1, smem);
  const __bf16* aB = wpA + lane * 8;
  bf16x8 pcur[4], pnxt[4];
#pragma unroll
  for (int kc = 0; kc < 4; ++kc) pcur[kc] = *(const bf16x8*)(aB + kc * 512);
  __syncthreads();
  f32x16 acc[2];
  acc[0] = zero16(); acc[1] = zero16();
  {
    const unsigned char* bB = smem + wid * RP66 + colb * TCS + kh8 * 2;
#pragma unroll
    for (int n = 0; n < 9; ++n) {
      if (n < 8) {
#pragma unroll
        for (int kc = 0; kc < 4; ++kc)
          pnxt[kc] = *(const bf16x8*)(aB + ((n + 1) * 4 + kc) * 512);
      }
      const int kh = n / 3, kw = n % 3;
#pragma unroll
      for (int kc = 0; kc < 4; ++kc) {
        const unsigned char* bp = bB + kh * RP66 + kw * TCS + kc * 32;
        bf16x8 b0 = *(const bf16x8*)(bp);
        bf16x8 b1 = *(const bf16x8*)(bp + 32 * TCS);
        acc[0] = mfma32(pcur[kc], b0, acc[0]);
        acc[1] = mfma32(pcur[kc], b1, acc[1]);
      }
#pragma unroll
      for (int kc = 0; kc < 4; ++kc) pcur[kc] = pnxt[kc];
    }
  }
  __syncthreads();
  unsigned char* reg = smem + wid * 9216;
#pragma unroll
  for (int pt = 0; pt < 2; ++pt)
#pragma unroll
    for (int g = 0; g < 4; ++g) {
      int o = half * 4 + g * 8;
      f32x4 v;
      v[0] = acc[pt][g * 4 + 0]; v[1] = acc[pt][g * 4 + 1];
      v[2] = acc[pt][g * 4 + 2]; v[3] = acc[pt][g * 4 + 3];
      *(f32x4*)(reg + ((pt * 32 + colb) * 36 + o) * 4) = v;
    }
  __builtin_amdgcn_s_waitcnt(0);
  size_t pix = (size_t)b * HW + (size_t)(h0 + wid) * 192 + w0 + lane;
#pragma unroll
  for (int q = 0; q < 5; ++q) {
    f32x4 v = *(const f32x4*)(reg + (lane * 36 + q * 4) * 4);
    v += *(const f32x4*)(bpad + q * 4);
    *(f32x4*)(off20 + pix * 20 + q * 4) = v;
  }
}

// ---------------- deformable conv (R3 version, unchanged) ----------------
__global__ __launch_bounds__(128, 2) void deform_mfma(
    const __bf16* __restrict__ frn, const float* __restrict__ off20,
    const __bf16* __restrict__ wdcA, float* __restrict__ xlow) {
  __shared__ __align__(16) unsigned char smem[2 * 18432];
  int b = blockIdx.x / 576, r = blockIdx.x % 576;
  int h = r / 3, ct = r % 3;
  int w0 = ct * 64;
  int wid = threadIdx.x >> 6, lane = threadIdx.x & 63;
  int wcol0 = w0 + wid * 32;
  unsigned char* wbase = smem + wid * 18432;
  float* goL = (float*)wbase;
  unsigned char* dbuf = wbase + 9216;
  const __bf16* xb = frn + (size_t)b * HW * 64;
  {
    int px = lane & 31, par = lane >> 5;
    int w = wcol0 + px;
    size_t pixl = (size_t)b * HW + (size_t)h * 192 + w;
    const float* ofp = off20 + pixl * 20;
    for (int n = par; n < 9; n += 2) {
      float offr = ofp[n], offc = ofp[9 + n];
      float pr = (float)(h + 1 + n / 3 - 1) + offr;
      float pc = (float)(w + 1 + n % 3 - 1) + offc;
      float prc = fminf(fmaxf(pr, 0.f), 193.f);
      float pcc = fminf(fmaxf(pc, 0.f), 193.f);
      float f0r = floorf(pr), f0c = floorf(pc);
      int qr0 = (int)fminf(fmaxf(f0r, 0.f), 193.f);
      int qc0 = (int)fminf(fmaxf(f0c, 0.f), 193.f);
      int qr1 = (int)fminf(fmaxf(f0r + 1.f, 0.f), 193.f);
      int qc1 = (int)fminf(fmaxf(f0c + 1.f, 0.f), 193.f);
      float dr0 = 1.f + ((float)qr0 - prc);
      float dr1 = 1.f - ((float)qr1 - prc);
      float dc0 = 1.f + ((float)qc0 - pcc);
      float dc1 = 1.f - ((float)qc1 - pcc);
      int o0, o1, o2, o3; float g0, g1, g2, g3;
      { bool v = (qr0 >= 1 && qr0 <= 192 && qc0 >= 1 && qc0 <= 192);
        o0 = min(max(qr0-1,0),191)*WW + min(max(qc0-1,0),191); g0 = v ? dr0*dc0 : 0.f; }
      { bool v = (qr1 >= 1 && qr1 <= 192 && qc1 >= 1 && qc1 <= 192);
        o1 = min(max(qr1-1,0),191)*WW + min(max(qc1-1,0),191); g1 = v ? dr1*dc1 : 0.f; }
      { bool v = (qr0 >= 1 && qr0 <= 192 && qc1 >= 1 && qc1 <= 192);
        o2 = min(max(qr0-1,0),191)*WW + min(max(qc1-1,0),191); g2 = v ? dr0*dc1 : 0.f; }
      { bool v = (qr1 >= 1 && qr1 <= 192 && qc0 >= 1 && qc0 <= 192);
        o3 = min(max(qr1-1,0),191)*WW + min(max(qc0-1,0),191); g3 = v ? dr1*dc0 : 0.f; }
      float* dst = goL + ((size_t)n * 32 + px) * 8;
      dst[0] = g0; dst[1] = g1; dst[2] = g2; dst[3] = g3;
      int* di = (int*)(dst + 4);
      di[0] = o0; di[1] = o1; di[2] = o2; di[3] = o3;
    }
  }
  f32x16 acc[2];
  acc[0] = zero16(); acc[1] = zero16();
  const __bf16* aB = wdcA + lane * 8;
  const int po = lane >> 3, cg = lane & 7;
  const int m = lane & 31, kh8 = (lane >> 5) << 3;
#pragma unroll
  for (int n = 0; n < 9; ++n) {
    unsigned char* buf = dbuf + (n & 1) * 4608;
#pragma unroll
    for (int i = 0; i < 4; ++i) {
      int px = po * 4 + i;
      const float* gsrc = goL + ((size_t)n * 32 + px) * 8;
      f32x4 g4 = *(const f32x4*)gsrc;
      const int* oi = (const int*)(gsrc + 4);
      bf16x8 c0 = *(const bf16x8*)(xb + (size_t)oi[0] * 64 + cg * 8);
      bf16x8 c1 = *(const bf16x8*)(xb + (size_t)oi[1] * 64 + cg * 8);
      bf16x8 c2 = *(const bf16x8*)(xb + (size_t)oi[2] * 64 + cg * 8);
      bf16x8 c3 = *(const bf16x8*)(xb + (size_t)oi[3] * 64 + cg * 8);
      bf16x8 ov;
#pragma unroll
      for (int e = 0; e < 8; ++e) {
        float f = g4[0] * (float)c0[e] + g4[1] * (float)c1[e] +
                  g4[2] * (float)c2[e] + g4[3] * (float)c3[e];
        ov[e] = (__bf16)f;
      }
      *(bf16x8*)(buf + px * TCS + cg * 16) = ov;
    }
    const unsigned char* bB = buf + m * TCS + kh8 * 2;
#pragma unroll
    for (int kc = 0; kc < 4; ++kc) {
      bf16x8 a0 = *(const bf16x8*)(aB + ((n * 4 + kc) * 2 + 0) * 512);
      bf16x8 a1 = *(const bf16x8*)(aB + ((n * 4 + kc) * 2 + 1) * 512);
      bf16x8 b0 = *(const bf16x8*)(bB + kc * 32);
      acc[0] = mfma32(a0, b0, acc[0]);
      acc[1] = mfma32(a1, b0, acc[1]);
    }
  }
  unsigned char* reg = dbuf;
  acc32_to_lds(acc, reg);
  __builtin_amdgcn_s_waitcnt(0);
  int colb = lane & 31, half = lane >> 5, ch = half * 32;
  float* dp = xlow + ((size_t)b * HW + (size_t)h * 192 + wcol0 + colb) * 64 + ch;
#pragma unroll
  for (int q = 0; q < 8; ++q)
    *(f32x4*)(dp + q * 4) = *(const f32x4*)(reg + (colb * 68 + ch + q * 4) * 4);
}

// ---------------- convcat: 128-thr block, tile 4r x 32c, wave = 2r x 32px ----------------
__global__ __launch_bounds__(128) void convcat_mfma(
    const float* __restrict__ xlow, const __bf16* __restrict__ frn,
    const __bf16* __restrict__ wA, const float* __restrict__ bias,
    float* __restrict__ y) {
  __shared__ __align__(16) unsigned char smem[LDSA];
  int b = blockIdx.x / 288, r = blockIdx.x % 288, rt = r / 6, ct = r % 6;
  int h0 = rt * 4, w0 = ct * 32;
  int wid = threadIdx.x >> 6, lane = threadIdx.x & 63;
  int m = lane & 31, kh8 = (lane >> 5) << 3;
  const unsigned char* bB = smem + (2 * wid) * RPA + m * TCS + kh8 * 2;
  f32x16 acc[2][2];
  acc[0][0] = zero16(); acc[0][1] = zero16(); acc[1][0] = zero16(); acc[1][1] = zero16();
  stage_f32T<6, 34, 128>(xlow + (size_t)b * HW * 64, 192, 192, h0 - 1, w0 - 1, smem);
  __syncthreads();
  kloopT<8, 0, RPA>(wA, bB, acc);
  __syncthreads();
  stage_bf16T<6, 34, 128>(frn + (size_t)b * HW * 64, 192, 192, h0 - 1, w0 - 1, smem);
  __syncthreads();
  kloopT<8, 4, RPA>(wA, bB, acc);
  __syncthreads();
  unsigned char* reg = smem + wid * TREG;
  int colb = m, ch = (lane >> 5) * 32;
#pragma unroll
  for (int pt = 0; pt < 2; ++pt) {
    acchalf_to_lds(acc, pt, reg);
    __builtin_amdgcn_s_waitcnt(0);
    f32x4 v[8];
    read_half(reg, v);
    int row = h0 + 2 * wid + pt;
    float* dp = y + ((size_t)b * HW + (size_t)row * 192 + w0 + colb) * 64 + ch;
#pragma unroll
    for (int q = 0; q < 8; ++q) {
      v[q] += *(const f32x4*)(bias + ch + q * 4);
      *(f32x4*)(dp + q * 4) = v[q];
    }
  }
}

// ---------------- conv1 + GDN + CELU: 128-thr block, tile 4r x 32c ----------------
__global__ __launch_bounds__(128) void conv1gdn_mfma(
    const float* __restrict__ y, const __bf16* __restrict__ w1A,
    const __bf16* __restrict__ gA, const float* __restrict__ beta,
    __bf16* __restrict__ hbuf) {
  __shared__ __align__(16) unsigned char smem[LDSA];
  int b = blockIdx.x / 288, r = blockIdx.x % 288, rt = r / 6, ct = r % 6;
  int h0 = rt * 4, w0 = ct * 32;
  int wid = threadIdx.x >> 6, lane = threadIdx.x & 63;
  int m = lane & 31, half = lane >> 5, kh8 = half << 3;
  int colb = m;
  const unsigned char* bB = smem + (2 * wid) * RPA + m * TCS + kh8 * 2;
  f32x16 acc[2][2];
  acc[0][0] = zero16(); acc[0][1] = zero16(); acc[1][0] = zero16(); acc[1][1] = zero16();
  stage_f32T<6, 34, 128>(y + (size_t)b * HW * 64, 192, 192, h0, w0, smem);
  __syncthreads();
  kloopT<4, 0, RPA>(w1A, bB, acc);
  __syncthreads();
  // v^2 into wave-private [64px][64ch] bf16 tile
  unsigned char* gdnreg = smem + wid * 9216;
#pragma unroll
  for (int ot = 0; ot < 2; ++ot)
#pragma unroll
    for (int pt = 0; pt < 2; ++pt)
#pragma unroll
      for (int g = 0; g < 4; ++g) {
        int o = ot * 32 + half * 4 + g * 8;
        int p = pt * 32 + colb;
        bf16x4 s;
#pragma unroll
        for (int e = 0; e < 4; ++e) {
          float x = acc[ot][pt][g * 4 + e];
          s[e] = (__bf16)(x * x);
        }
        *(bf16x4*)(gdnreg + p * GDNPITCH + o * 2) = s;
      }
  __builtin_amdgcn_s_waitcnt(0);
  f32x16 nacc[2][2];
  nacc[0][0] = zero16(); nacc[0][1] = zero16(); nacc[1][0] = zero16(); nacc[1][1] = zero16();
  {
    const __bf16* gaB = gA + lane * 8;
    const unsigned char* gb = gdnreg + colb * GDNPITCH + kh8 * 2;
#pragma unroll
    for (int kc = 0; kc < 4; ++kc) {
      bf16x8 ga0 = *(const bf16x8*)(gaB + (kc * 2 + 0) * 512);
      bf16x8 ga1 = *(const bf16x8*)(gaB + (kc * 2 + 1) * 512);
      bf16x8 b0 = *(const bf16x8*)(gb + kc * 32);
      bf16x8 b1 = *(const bf16x8*)(gb + 32 * GDNPITCH + kc * 32);
      nacc[0][0] = mfma32(ga0, b0, nacc[0][0]);
      nacc[0][1] = mfma32(ga0, b1, nacc[0][1]);
      nacc[1][0] = mfma32(ga1, b0, nacc[1][0]);
      nacc[1][1] = mfma32(ga1, b1, nacc[1][1]);
    }
  }
#pragma unroll
  for (int ot = 0; ot < 2; ++ot)
#pragma unroll
    for (int g = 0; g < 4; ++g) {
      f32x4 bet = *(const f32x4*)(beta + ot * 32 + half * 4 + g * 8);
#pragma unroll
      for (int pt = 0; pt < 2; ++pt)
#pragma unroll
        for (int e = 0; e < 4; ++e) {
          float nv = bet[e] + nacc[ot][pt][g * 4 + e];
          float hv = acc[ot][pt][g * 4 + e] * rsqrtf(nv);
          hv = hv > 0.f ? hv : expf(hv) - 1.f;
          acc[ot][pt][g * 4 + e] = hv;
        }
    }
  __syncthreads();  // other wave's GDN reads done before TREG overlays
  unsigned char* reg = smem + wid * TREG;
  int ch = half * 32;
#pragma unroll
  for (int pt = 0; pt < 2; ++pt) {
    acchalf_to_lds(acc, pt, reg);
    __builtin_amdgcn_s_waitcnt(0);
    f32x4 v[8];
    read_half(reg, v);
    int hr = h0 + 2 * wid + pt, wcol = w0 + colb;
    if (hr < 190 && wcol < 190) {
      __bf16* dp = hbuf + ((size_t)b * HW1 + (size_t)hr * 190 + wcol) * 64 + ch;
#pragma unroll
      for (int q = 0; q < 8; ++q) {
        bf16x4 o;
#pragma unroll
        for (int e = 0; e < 4; ++e) o[e] = (__bf16)v[q][e];
        *(bf16x4*)(dp + q * 4) = o;
      }
    }
  }
}

// ---------------- conv2 (pad 2) + residual: 128-thr block, tile 4r x 32c ----------------
template <bool LAST>
__global__ __launch_bounds__(128) void conv2_mfma(
    const __bf16* __restrict__ hbuf, const __bf16* __restrict__ w2A,
    const float* __restrict__ xlow, float* __restrict__ y,
    float* __restrict__ out) {
  __shared__ __align__(16) unsigned char smem[LDSB];
  int b = blockIdx.x / 288, r = blockIdx.x % 288, rt = r / 6, ct = r % 6;
  int h0 = rt * 4, w0 = ct * 32;
  int wid = threadIdx.x >> 6, lane = threadIdx.x & 63;
  int m = lane & 31, kh8 = (lane >> 5) << 3;
  int colb = m, ch = (lane >> 5) * 32;
  const unsigned char* bB = smem + (2 * wid) * RPB + m * TCS + kh8 * 2;
  f32x16 acc[2][2];
  acc[0][0] = zero16(); acc[0][1] = zero16(); acc[1][0] = zero16(); acc[1][1] = zero16();
  stage_bf16T<8, 36, 128>(hbuf + (size_t)b * HW1 * 64, 190, 190, h0 - 2, w0 - 2, smem);
  __syncthreads();
  kloopT<4, 0, RPB>(w2A, bB, acc);
  __syncthreads();
  unsigned char* reg = smem + wid * TREG;
#pragma unroll
  for (int pt = 0; pt < 2; ++pt) {
    acchalf_to_lds(acc, pt, reg);
    __builtin_amdgcn_s_waitcnt(0);
    f32x4 v[8];
    read_half(reg, v);
    int row = h0 + 2 * wid + pt;
    size_t pix = (size_t)b * HW + (size_t)row * 192 + w0 + colb;
    float* yp = y + pix * 64 + ch;
#pragma unroll
    for (int q = 0; q < 8; ++q) v[q] += *(const f32x4*)(yp + q * 4);
    if (!LAST) {
#pragma unroll
      for (int q = 0; q < 8; ++q) *(f32x4*)(yp + q * 4) = v[q];
    } else {
      const float* xp = xlow + pix * 64 + ch;
#pragma unroll
      for (int q = 0; q < 8; ++q) v[q] += *(const f32x4*)(xp + q * 4);
#pragma unroll
      for (int q = 0; q < 8; ++q)
        *(f32x4*)(reg + (colb * 68 + ch + q * 4) * 4) = v[q];
      __builtin_amdgcn_s_waitcnt(0);
      int o = lane;
      float* op = out + ((size_t)b * 64 + o) * HW + (size_t)row * 192 + w0;
#pragma unroll
      for (int q = 0; q < 8; ++q) {
        f32x4 s;
#pragma unroll
        for (int e = 0; e < 4; ++e)
          s[e] = *(const float*)(reg + ((q * 4 + e) * 68 + o) * 4);
        *(f32x4*)(op + q * 4) = s;
      }
    }
  }
}

extern "C" void kernel_launch(void* const* d_in, const int* in_sizes, int n_in,
                              void* d_out, int out_size, void* d_ws, size_t ws_size,
                              hipStream_t stream) {
  const float* f_r      = (const float*)d_in[0];
  const float* m_t      = (const float*)d_in[1];
  const float* w_pconv  = (const float*)d_in[2];
  const float* b_pconv  = (const float*)d_in[3];
  const float* w_dc     = (const float*)d_in[4];
  const float* w_cat    = (const float*)d_in[5];
  const float* b_cat    = (const float*)d_in[6];
  const float* rb_w1    = (const float*)d_in[7];
  const float* rb_w2    = (const float*)d_in[8];
  const float* rb_beta  = (const float*)d_in[9];
  const float* rb_gamma = (const float*)d_in[10];
  float* out = (float*)d_out;

  float* ws = (float*)d_ws;
  float*  xlow  = ws;                         // [2][HW][64] f32
  float*  ybuf  = xlow + 4718592;             // [2][HW][64] f32
  float*  off20 = ybuf + 4718592;             // [2][HW][20] f32
  __bf16* frn   = (__bf16*)(off20 + 1474560); // [2][HW][64] bf16
  __bf16* mtn   = (__bf16*)(off20 + 1474560 + 2359296);
  __bf16* hbuf  = mtn;                        // mtn dead after pconv
  float*  wbase = off20 + 1474560 + 2359296 + 2359296;
  __bf16* wpA   = (__bf16*)wbase;
  __bf16* wdcA  = (__bf16*)(wbase + 9216);
  __bf16* wcatA = (__bf16*)(wbase + 27648);
  __bf16* w1A   = (__bf16*)(wbase + 64512);
  __bf16* w2A   = (__bf16*)(wbase + 119808);
  __bf16* gA    = (__bf16*)(wbase + 175104);
  float*  bpad  = wbase + 181248;

  prep_weights<<<1417, 256, 0, stream>>>(w_pconv, b_pconv, w_dc, w_cat, rb_w1, rb_w2,
                                         rb_gamma, wpA, wdcA, wcatA, w1A, w2A, gA, bpad);
  to_nhwc_bf16<<<2304, 256, 0, stream>>>(f_r, m_t, frn, mtn);
  pconv_mfma<<<288, 256, 0, stream>>>(mtn, wpA, bpad, off20);
  deform_mfma<<<1152, 128, 0, stream>>>(frn, off20, wdcA, xlow);
  convcat_mfma<<<576, 128, 0, stream>>>(xlow, frn, wcatA, b_cat, ybuf);
  for (int l = 0; l < 3; ++l) {
    conv1gdn_mfma<<<576, 128, 0, stream>>>(ybuf, w1A + l * 36864, gA + l * 4096,
                                           rb_beta + l * 64, hbuf);
    if (l < 2)
      conv2_mfma<false><<<576, 128, 0, stream>>>(hbuf, w2A + l * 36864, xlow, ybuf, out);
    else
      conv2_mfma<true><<<576, 128, 0, stream>>>(hbuf, w2A + l * 36864, xlow, ybuf, out);
  }
}

// Round 8
// 352.879 us; speedup vs baseline: 1.0924x; 1.0360x over previous
//
#include <hip/hip_runtime.h>

typedef __attribute__((ext_vector_type(8))) __bf16 bf16x8;
typedef __attribute__((ext_vector_type(4))) __bf16 bf16x4;
typedef __attribute__((ext_vector_type(16))) float f32x16;
typedef __attribute__((ext_vector_type(4))) float f32x4;

#define HH 192
#define WW 192
#define HW 36864
#define HW1 36100

#define TCS 144                  // bytes per staged col: 64 bf16 = 128B + 16B pad
#define RP66 (66 * TCS)          // pconv staging row pitch
#define RPA (34 * TCS)           // 4896: pad-1 tiles (4 rows x 34 cols)
#define RPB (36 * TCS)           // 5184: conv2 pad-2 tiles (6 rows x 36 cols)
#define LDSA (4 * RPA)           // 19584
#define LDSB (6 * RPB)           // 31104
#define GDNPITCH 144
#define TREG 8704                // transpose region: 32 px x 68 f32

__device__ inline f32x16 mfma32(bf16x8 a, bf16x8 b, f32x16 c) {
  return __builtin_amdgcn_mfma_f32_32x32x16_bf16(a, b, c, 0, 0, 0);
}

__device__ inline f32x16 zero16() {
  f32x16 z;
#pragma unroll
  for (int e = 0; e < 16; ++e) z[e] = 0.f;
  return z;
}

// ---------------- weight prep: MFMA A-fragment layouts ----------------
__global__ __launch_bounds__(256) void prep_weights(
    const float* __restrict__ wp, const float* __restrict__ bp,
    const float* __restrict__ wdc, const float* __restrict__ wcat,
    const float* __restrict__ w1, const float* __restrict__ w2,
    const float* __restrict__ gamma,
    __bf16* __restrict__ wpA, __bf16* __restrict__ wdcA,
    __bf16* __restrict__ wcatA, __bf16* __restrict__ w1A,
    __bf16* __restrict__ w2A, __bf16* __restrict__ gA,
    float* __restrict__ bpad) {
  int i = blockIdx.x * 256 + threadIdx.x;
  if (i < 18432) {
    int j = i & 7, lane = (i >> 3) & 63, kc = (i >> 9) & 3, n = i >> 11;
    int o = lane & 31, c = kc * 16 + ((lane >> 5) << 3) + j;
    wpA[i] = (o < 18) ? (__bf16)wp[(o * 64 + c) * 9 + n] : (__bf16)0.f;
    return;
  }
  i -= 18432;
  if (i < 36864) {
    int j = i & 7, lane = (i >> 3) & 63, ot = (i >> 9) & 1, kc = (i >> 10) & 3, n = i >> 12;
    int o = ot * 32 + (lane & 31), c = kc * 16 + ((lane >> 5) << 3) + j;
    wdcA[i] = (__bf16)wdc[(o * 64 + c) * 9 + n];
    return;
  }
  i -= 36864;
  if (i < 73728) {
    int d = i, j = d & 7; d >>= 3; int lane = d & 63; d >>= 6; int ot = d & 1; d >>= 1;
    int kc = d & 7; int n = d >> 3;
    int o = ot * 32 + (lane & 31), c = kc * 16 + ((lane >> 5) << 3) + j;
    wcatA[i] = (__bf16)wcat[(o * 128 + c) * 9 + n];
    return;
  }
  i -= 73728;
  if (i < 110592) {
    int l = i / 36864, di = i % 36864, d = di;
    int j = d & 7; d >>= 3; int lane = d & 63; d >>= 6; int ot = d & 1; d >>= 1;
    int kc = d & 3; int n = d >> 2;
    int o = ot * 32 + (lane & 31), c = kc * 16 + ((lane >> 5) << 3) + j;
    w1A[l * 36864 + di] = (__bf16)w1[l * 36864 + (o * 64 + c) * 9 + n];
    return;
  }
  i -= 110592;
  if (i < 110592) {
    int l = i / 36864, di = i % 36864, d = di;
    int j = d & 7; d >>= 3; int lane = d & 63; d >>= 6; int ot = d & 1; d >>= 1;
    int kc = d & 3; int n = d >> 2;
    int o = ot * 32 + (lane & 31), c = kc * 16 + ((lane >> 5) << 3) + j;
    w2A[l * 36864 + di] = (__bf16)w2[l * 36864 + (o * 64 + c) * 9 + n];
    return;
  }
  i -= 110592;
  if (i < 12288) {
    int l = i / 4096, di = i % 4096, d = di;
    int j = d & 7; d >>= 3; int lane = d & 63; d >>= 6; int ot = d & 1; d >>= 1;
    int kc = d & 3;
    int o = ot * 32 + (lane & 31), c = kc * 16 + ((lane >> 5) << 3) + j;
    gA[l * 4096 + di] = (__bf16)gamma[l * 4096 + o * 64 + c];
    return;
  }
  i -= 12288;
  if (i < 20) bpad[i] = (i < 18) ? bp[i] : 0.f;
}

// ---------------- NCHW fp32 -> NHWC bf16 transpose (f_r and m_t) ----------------
__global__ __launch_bounds__(256) void to_nhwc_bf16(
    const float* __restrict__ fr, const float* __restrict__ mt,
    __bf16* __restrict__ frn, __bf16* __restrict__ mtn) {
  __shared__ __align__(16) __bf16 tile[64 * 72];
  int tensor = blockIdx.x / 1152, rem = blockIdx.x % 1152;
  int b = rem / 576, p0 = (rem % 576) * 64;
  const float* src = (tensor ? mt : fr) + (size_t)b * 64 * HW;
  __bf16* dst = (tensor ? mtn : frn) + (size_t)b * HW * 64;
  int tid = threadIdx.x, c = tid >> 2, q0 = (tid & 3) * 16;
  const float* sp = src + (size_t)c * HW + p0 + q0;
#pragma unroll
  for (int qq = 0; qq < 4; ++qq) {
    f32x4 v = *(const f32x4*)(sp + qq * 4);
#pragma unroll
    for (int e = 0; e < 4; ++e) tile[(q0 + qq * 4 + e) * 72 + c] = (__bf16)v[e];
  }
  __syncthreads();
  int px = tid >> 2, c0 = (tid & 3) * 16;
  bf16x8 a = *(const bf16x8*)(&tile[px * 72 + c0]);
  bf16x8 b8 = *(const bf16x8*)(&tile[px * 72 + c0 + 8]);
  __bf16* dp = dst + (size_t)(p0 + px) * 64 + c0;
  *(bf16x8*)dp = a;
  *(bf16x8*)(dp + 8) = b8;
}

// ---------------- staging loops ----------------
template <int ROWS, int COLS, int TPB>
__device__ inline void stage_f32T(const float* __restrict__ src,
                                  int srcH, int srcW, int row0, int col0,
                                  unsigned char* lds) {
  for (int i = threadIdx.x; i < ROWS * COLS * 16; i += TPB) {
    int r = i / (COLS * 16), rem = i - r * (COLS * 16), j = rem >> 4, q = rem & 15;
    int gr = row0 + r, gc = col0 + j;
    f32x4 v = {0.f, 0.f, 0.f, 0.f};
    if (gr >= 0 && gr < srcH && gc >= 0 && gc < srcW)
      v = *(const f32x4*)(src + ((size_t)gr * srcW + gc) * 64 + q * 4);
    bf16x4 o;
#pragma unroll
    for (int e = 0; e < 4; ++e) o[e] = (__bf16)v[e];
    *(bf16x4*)(lds + r * (COLS * TCS) + j * TCS + q * 8) = o;
  }
}

template <int ROWS, int COLS, int TPB>
__device__ inline void stage_bf16T(const __bf16* __restrict__ src,
                                   int srcH, int srcW, int row0, int col0,
                                   unsigned char* lds) {
  for (int i = threadIdx.x; i < ROWS * COLS * 8; i += TPB) {
    int r = i / (COLS * 8), rem = i - r * (COLS * 8), j = rem >> 3, u = rem & 7;
    int gr = row0 + r, gc = col0 + j;
    bf16x8 v;
#pragma unroll
    for (int e = 0; e < 8; ++e) v[e] = (__bf16)0.f;
    if (gr >= 0 && gr < srcH && gc >= 0 && gc < srcW)
      v = *(const bf16x8*)(src + ((size_t)gr * srcW + gc) * 64 + u * 8);
    *(bf16x8*)(lds + r * (COLS * TCS) + j * TCS + u * 16) = v;
  }
}

// ---------------- K-loop: wave tile 64o x 64px (2 rows x 32 cols; b1 = +RP) ----------------
template <int KC, int KOFFA, int RP>
__device__ inline void kloopT(const __bf16* __restrict__ wA,
                              const unsigned char* __restrict__ bB,
                              f32x16 acc[2][2]) {
  const int lane = threadIdx.x & 63;
  const __bf16* aB = wA + lane * 8;
#pragma unroll
  for (int n = 0; n < 9; ++n) {
    const int kh = n / 3, kw = n % 3;
#pragma unroll
    for (int kc = 0; kc < 4; ++kc) {
      bf16x8 a0 = *(const bf16x8*)(aB + ((n * KC + KOFFA + kc) * 2 + 0) * 512);
      bf16x8 a1 = *(const bf16x8*)(aB + ((n * KC + KOFFA + kc) * 2 + 1) * 512);
      const unsigned char* bp = bB + kh * RP + kw * TCS + kc * 32;
      bf16x8 b0 = *(const bf16x8*)(bp);
      bf16x8 b1 = *(const bf16x8*)(bp + RP);   // second px-half = next image row
      acc[0][0] = mfma32(a0, b0, acc[0][0]);
      acc[0][1] = mfma32(a0, b1, acc[0][1]);
      acc[1][0] = mfma32(a1, b0, acc[1][0]);
      acc[1][1] = mfma32(a1, b1, acc[1][1]);
    }
  }
}

// ---------------- epilogue helpers ----------------
__device__ inline void acchalf_to_lds(const f32x16 acc[2][2], int pt, unsigned char* reg) {
  int lane = threadIdx.x & 63;
  int colb = lane & 31, half = lane >> 5;
#pragma unroll
  for (int ot = 0; ot < 2; ++ot)
#pragma unroll
    for (int g = 0; g < 4; ++g) {
      int o = ot * 32 + half * 4 + g * 8;
      f32x4 v;
      v[0] = acc[ot][pt][g * 4 + 0]; v[1] = acc[ot][pt][g * 4 + 1];
      v[2] = acc[ot][pt][g * 4 + 2]; v[3] = acc[ot][pt][g * 4 + 3];
      *(f32x4*)(reg + (colb * 68 + o) * 4) = v;
    }
}

__device__ inline void read_half(const unsigned char* reg, f32x4 v[8]) {
  int lane = threadIdx.x & 63;
  int col = lane & 31, ch = (lane >> 5) * 32;
#pragma unroll
  for (int q = 0; q < 8; ++q)
    v[q] = *(const f32x4*)(reg + (col * 68 + ch + q * 4) * 4);
}

__device__ inline void acc32_to_lds(const f32x16 acc[2], unsigned char* reg) {
  int lane = threadIdx.x & 63;
  int colb = lane & 31, half = lane >> 5;
#pragma unroll
  for (int ot = 0; ot < 2; ++ot)
#pragma unroll
    for (int g = 0; g < 4; ++g) {
      int o = ot * 32 + half * 4 + g * 8;
      f32x4 v;
      v[0] = acc[ot][g * 4 + 0]; v[1] = acc[ot][g * 4 + 1];
      v[2] = acc[ot][g * 4 + 2]; v[3] = acc[ot][g * 4 + 3];
      *(f32x4*)(reg + (colb * 68 + o) * 4) = v;
    }
}

// ---------------- pconv MFMA (unchanged) ----------------
__global__ __launch_bounds__(256, 1) void pconv_mfma(
    const __bf16* __restrict__ mtn, const __bf16* __restrict__ wpA,
    const float* __restrict__ bpad, float* __restrict__ off20) {
  __shared__ __align__(16) unsigned char smem[6 * RP66];
  int b = blockIdx.x / 144, r = blockIdx.x % 144, rt = r / 3, ct = r % 3;
  int h0 = rt * 4, w0 = ct * 64;
  int wid = threadIdx.x >> 6, lane = threadIdx.x & 63;
  int colb = lane & 31, half = lane >> 5, kh8 = half << 3;
  stage_bf16T<6, 66, 256>(mtn + (size_t)b * HW * 64, 192, 192, h0 - 1, w0 - 1, smem);
  const __bf16* aB = wpA + lane * 8;
  bf16x8 pcur[4], pnxt[4];
#pragma unroll
  for (int kc = 0; kc < 4; ++kc) pcur[kc] = *(const bf16x8*)(aB + kc * 512);
  __syncthreads();
  f32x16 acc[2];
  acc[0] = zero16(); acc[1] = zero16();
  {
    const unsigned char* bB = smem + wid * RP66 + colb * TCS + kh8 * 2;
#pragma unroll
    for (int n = 0; n < 9; ++n) {
      if (n < 8) {
#pragma unroll
        for (int kc = 0; kc < 4; ++kc)
          pnxt[kc] = *(const bf16x8*)(aB + ((n + 1) * 4 + kc) * 512);
      }
      const int kh = n / 3, kw = n % 3;
#pragma unroll
      for (int kc = 0; kc < 4; ++kc) {
        const unsigned char* bp = bB + kh * RP66 + kw * TCS + kc * 32;
        bf16x8 b0 = *(const bf16x8*)(bp);
        bf16x8 b1 = *(const bf16x8*)(bp + 32 * TCS);
        acc[0] = mfma32(pcur[kc], b0, acc[0]);
        acc[1] = mfma32(pcur[kc], b1, acc[1]);
      }
#pragma unroll
      for (int kc = 0; kc < 4; ++kc) pcur[kc] = pnxt[kc];
    }
  }
  __syncthreads();
  unsigned char* reg = smem + wid * 9216;
#pragma unroll
  for (int pt = 0; pt < 2; ++pt)
#pragma unroll
    for (int g = 0; g < 4; ++g) {
      int o = half * 4 + g * 8;
      f32x4 v;
      v[0] = acc[pt][g * 4 + 0]; v[1] = acc[pt][g * 4 + 1];
      v[2] = acc[pt][g * 4 + 2]; v[3] = acc[pt][g * 4 + 3];
      *(f32x4*)(reg + ((pt * 32 + colb) * 36 + o) * 4) = v;
    }
  __builtin_amdgcn_s_waitcnt(0);
  size_t pix = (size_t)b * HW + (size_t)(h0 + wid) * 192 + w0 + lane;
#pragma unroll
  for (int q = 0; q < 5; ++q) {
    f32x4 v = *(const f32x4*)(reg + (lane * 36 + q * 4) * 4);
    v += *(const f32x4*)(bpad + q * 4);
    *(f32x4*)(off20 + pix * 20 + q * 4) = v;
  }
}

// ---------------- deformable conv (unchanged) ----------------
__global__ __launch_bounds__(128, 2) void deform_mfma(
    const __bf16* __restrict__ frn, const float* __restrict__ off20,
    const __bf16* __restrict__ wdcA, float* __restrict__ xlow) {
  __shared__ __align__(16) unsigned char smem[2 * 18432];
  int b = blockIdx.x / 576, r = blockIdx.x % 576;
  int h = r / 3, ct = r % 3;
  int w0 = ct * 64;
  int wid = threadIdx.x >> 6, lane = threadIdx.x & 63;
  int wcol0 = w0 + wid * 32;
  unsigned char* wbase = smem + wid * 18432;
  float* goL = (float*)wbase;
  unsigned char* dbuf = wbase + 9216;
  const __bf16* xb = frn + (size_t)b * HW * 64;
  {
    int px = lane & 31, par = lane >> 5;
    int w = wcol0 + px;
    size_t pixl = (size_t)b * HW + (size_t)h * 192 + w;
    const float* ofp = off20 + pixl * 20;
    for (int n = par; n < 9; n += 2) {
      float offr = ofp[n], offc = ofp[9 + n];
      float pr = (float)(h + 1 + n / 3 - 1) + offr;
      float pc = (float)(w + 1 + n % 3 - 1) + offc;
      float prc = fminf(fmaxf(pr, 0.f), 193.f);
      float pcc = fminf(fmaxf(pc, 0.f), 193.f);
      float f0r = floorf(pr), f0c = floorf(pc);
      int qr0 = (int)fminf(fmaxf(f0r, 0.f), 193.f);
      int qc0 = (int)fminf(fmaxf(f0c, 0.f), 193.f);
      int qr1 = (int)fminf(fmaxf(f0r + 1.f, 0.f), 193.f);
      int qc1 = (int)fminf(fmaxf(f0c + 1.f, 0.f), 193.f);
      float dr0 = 1.f + ((float)qr0 - prc);
      float dr1 = 1.f - ((float)qr1 - prc);
      float dc0 = 1.f + ((float)qc0 - pcc);
      float dc1 = 1.f - ((float)qc1 - pcc);
      int o0, o1, o2, o3; float g0, g1, g2, g3;
      { bool v = (qr0 >= 1 && qr0 <= 192 && qc0 >= 1 && qc0 <= 192);
        o0 = min(max(qr0-1,0),191)*WW + min(max(qc0-1,0),191); g0 = v ? dr0*dc0 : 0.f; }
      { bool v = (qr1 >= 1 && qr1 <= 192 && qc1 >= 1 && qc1 <= 192);
        o1 = min(max(qr1-1,0),191)*WW + min(max(qc1-1,0),191); g1 = v ? dr1*dc1 : 0.f; }
      { bool v = (qr0 >= 1 && qr0 <= 192 && qc1 >= 1 && qc1 <= 192);
        o2 = min(max(qr0-1,0),191)*WW + min(max(qc1-1,0),191); g2 = v ? dr0*dc1 : 0.f; }
      { bool v = (qr1 >= 1 && qr1 <= 192 && qc0 >= 1 && qc0 <= 192);
        o3 = min(max(qr1-1,0),191)*WW + min(max(qc0-1,0),191); g3 = v ? dr1*dc0 : 0.f; }
      float* dst = goL + ((size_t)n * 32 + px) * 8;
      dst[0] = g0; dst[1] = g1; dst[2] = g2; dst[3] = g3;
      int* di = (int*)(dst + 4);
      di[0] = o0; di[1] = o1; di[2] = o2; di[3] = o3;
    }
  }
  f32x16 acc[2];
  acc[0] = zero16(); acc[1] = zero16();
  const __bf16* aB = wdcA + lane * 8;
  const int po = lane >> 3, cg = lane & 7;
  const int m = lane & 31, kh8 = (lane >> 5) << 3;
#pragma unroll
  for (int n = 0; n < 9; ++n) {
    unsigned char* buf = dbuf + (n & 1) * 4608;
#pragma unroll
    for (int i = 0; i < 4; ++i) {
      int px = po * 4 + i;
      const float* gsrc = goL + ((size_t)n * 32 + px) * 8;
      f32x4 g4 = *(const f32x4*)gsrc;
      const int* oi = (const int*)(gsrc + 4);
      bf16x8 c0 = *(const bf16x8*)(xb + (size_t)oi[0] * 64 + cg * 8);
      bf16x8 c1 = *(const bf16x8*)(xb + (size_t)oi[1] * 64 + cg * 8);
      bf16x8 c2 = *(const bf16x8*)(xb + (size_t)oi[2] * 64 + cg * 8);
      bf16x8 c3 = *(const bf16x8*)(xb + (size_t)oi[3] * 64 + cg * 8);
      bf16x8 ov;
#pragma unroll
      for (int e = 0; e < 8; ++e) {
        float f = g4[0] * (float)c0[e] + g4[1] * (float)c1[e] +
                  g4[2] * (float)c2[e] + g4[3] * (float)c3[e];
        ov[e] = (__bf16)f;
      }
      *(bf16x8*)(buf + px * TCS + cg * 16) = ov;
    }
    const unsigned char* bB = buf + m * TCS + kh8 * 2;
#pragma unroll
    for (int kc = 0; kc < 4; ++kc) {
      bf16x8 a0 = *(const bf16x8*)(aB + ((n * 4 + kc) * 2 + 0) * 512);
      bf16x8 a1 = *(const bf16x8*)(aB + ((n * 4 + kc) * 2 + 1) * 512);
      bf16x8 b0 = *(const bf16x8*)(bB + kc * 32);
      acc[0] = mfma32(a0, b0, acc[0]);
      acc[1] = mfma32(a1, b0, acc[1]);
    }
  }
  unsigned char* reg = dbuf;
  acc32_to_lds(acc, reg);
  __builtin_amdgcn_s_waitcnt(0);
  int colb = lane & 31, half = lane >> 5, ch = half * 32;
  float* dp = xlow + ((size_t)b * HW + (size_t)h * 192 + wcol0 + colb) * 64 + ch;
#pragma unroll
  for (int q = 0; q < 8; ++q)
    *(f32x4*)(dp + q * 4) = *(const f32x4*)(reg + (colb * 68 + ch + q * 4) * 4);
}

// ---------------- convcat: 1-wave block, tile 2r x 32c, y -> bf16 ----------------
__global__ __launch_bounds__(64, 1) void convcat_mfma(
    const float* __restrict__ xlow, const __bf16* __restrict__ frn,
    const __bf16* __restrict__ wA, const float* __restrict__ bias,
    __bf16* __restrict__ y) {
  __shared__ __align__(16) unsigned char smem[LDSA];
  int b = blockIdx.x / 576, r = blockIdx.x % 576, rt = r / 6, ct = r % 6;
  int h0 = rt * 2, w0 = ct * 32;
  int lane = threadIdx.x & 63;
  int m = lane & 31, kh8 = (lane >> 5) << 3;
  const unsigned char* bB = smem + m * TCS + kh8 * 2;
  f32x16 acc[2][2];
  acc[0][0] = zero16(); acc[0][1] = zero16(); acc[1][0] = zero16(); acc[1][1] = zero16();
  stage_f32T<4, 34, 64>(xlow + (size_t)b * HW * 64, 192, 192, h0 - 1, w0 - 1, smem);
  __builtin_amdgcn_s_waitcnt(0);
  kloopT<8, 0, RPA>(wA, bB, acc);
  __builtin_amdgcn_s_waitcnt(0);
  stage_bf16T<4, 34, 64>(frn + (size_t)b * HW * 64, 192, 192, h0 - 1, w0 - 1, smem);
  __builtin_amdgcn_s_waitcnt(0);
  kloopT<8, 4, RPA>(wA, bB, acc);
  __builtin_amdgcn_s_waitcnt(0);
  unsigned char* reg = smem;
  int colb = m, ch = (lane >> 5) * 32;
#pragma unroll
  for (int pt = 0; pt < 2; ++pt) {
    acchalf_to_lds(acc, pt, reg);
    __builtin_amdgcn_s_waitcnt(0);
    f32x4 v[8];
    read_half(reg, v);
    int row = h0 + pt;
    __bf16* dp = y + ((size_t)b * HW + (size_t)row * 192 + w0 + colb) * 64 + ch;
#pragma unroll
    for (int q = 0; q < 8; ++q) {
      v[q] += *(const f32x4*)(bias + ch + q * 4);
      bf16x4 o;
#pragma unroll
      for (int e = 0; e < 4; ++e) o[e] = (__bf16)v[q][e];
      *(bf16x4*)(dp + q * 4) = o;
    }
    __builtin_amdgcn_s_waitcnt(0);
  }
}

// ---------------- conv1 + GDN + CELU: 1-wave block, tile 2r x 32c, y bf16 in ----------------
__global__ __launch_bounds__(64, 1) void conv1gdn_mfma(
    const __bf16* __restrict__ y, const __bf16* __restrict__ w1A,
    const __bf16* __restrict__ gA, const float* __restrict__ beta,
    __bf16* __restrict__ hbuf) {
  __shared__ __align__(16) unsigned char smem[LDSA];
  int b = blockIdx.x / 576, r = blockIdx.x % 576, rt = r / 6, ct = r % 6;
  int h0 = rt * 2, w0 = ct * 32;
  int lane = threadIdx.x & 63;
  int m = lane & 31, half = lane >> 5, kh8 = half << 3;
  int colb = m;
  const unsigned char* bB = smem + m * TCS + kh8 * 2;
  f32x16 acc[2][2];
  acc[0][0] = zero16(); acc[0][1] = zero16(); acc[1][0] = zero16(); acc[1][1] = zero16();
  stage_bf16T<4, 34, 64>(y + (size_t)b * HW * 64, 192, 192, h0, w0, smem);
  __builtin_amdgcn_s_waitcnt(0);
  kloopT<4, 0, RPA>(w1A, bB, acc);
  __builtin_amdgcn_s_waitcnt(0);
  // v^2 into [64px][64ch] bf16 tile at smem
  unsigned char* gdnreg = smem;
#pragma unroll
  for (int ot = 0; ot < 2; ++ot)
#pragma unroll
    for (int pt = 0; pt < 2; ++pt)
#pragma unroll
      for (int g = 0; g < 4; ++g) {
        int o = ot * 32 + half * 4 + g * 8;
        int p = pt * 32 + colb;
        bf16x4 s;
#pragma unroll
        for (int e = 0; e < 4; ++e) {
          float x = acc[ot][pt][g * 4 + e];
          s[e] = (__bf16)(x * x);
        }
        *(bf16x4*)(gdnreg + p * GDNPITCH + o * 2) = s;
      }
  __builtin_amdgcn_s_waitcnt(0);
  f32x16 nacc[2][2];
  nacc[0][0] = zero16(); nacc[0][1] = zero16(); nacc[1][0] = zero16(); nacc[1][1] = zero16();
  {
    const __bf16* gaB = gA + lane * 8;
    const unsigned char* gb = gdnreg + colb * GDNPITCH + kh8 * 2;
#pragma unroll
    for (int kc = 0; kc < 4; ++kc) {
      bf16x8 ga0 = *(const bf16x8*)(gaB + (kc * 2 + 0) * 512);
      bf16x8 ga1 = *(const bf16x8*)(gaB + (kc * 2 + 1) * 512);
      bf16x8 b0 = *(const bf16x8*)(gb + kc * 32);
      bf16x8 b1 = *(const bf16x8*)(gb + 32 * GDNPITCH + kc * 32);
      nacc[0][0] = mfma32(ga0, b0, nacc[0][0]);
      nacc[0][1] = mfma32(ga0, b1, nacc[0][1]);
      nacc[1][0] = mfma32(ga1, b0, nacc[1][0]);
      nacc[1][1] = mfma32(ga1, b1, nacc[1][1]);
    }
  }
#pragma unroll
  for (int ot = 0; ot < 2; ++ot)
#pragma unroll
    for (int g = 0; g < 4; ++g) {
      f32x4 bet = *(const f32x4*)(beta + ot * 32 + half * 4 + g * 8);
#pragma unroll
      for (int pt = 0; pt < 2; ++pt)
#pragma unroll
        for (int e = 0; e < 4; ++e) {
          float nv = bet[e] + nacc[ot][pt][g * 4 + e];
          float hv = acc[ot][pt][g * 4 + e] * rsqrtf(nv);
          hv = hv > 0.f ? hv : expf(hv) - 1.f;
          acc[ot][pt][g * 4 + e] = hv;
        }
    }
  __builtin_amdgcn_s_waitcnt(0);
  unsigned char* reg = smem + 9216;   // past gdn tile (9216 + 8704 <= 19584)
  int ch = half * 32;
#pragma unroll
  for (int pt = 0; pt < 2; ++pt) {
    acchalf_to_lds(acc, pt, reg);
    __builtin_amdgcn_s_waitcnt(0);
    f32x4 v[8];
    read_half(reg, v);
    int hr = h0 + pt, wcol = w0 + colb;
    if (hr < 190 && wcol < 190) {
      __bf16* dp = hbuf + ((size_t)b * HW1 + (size_t)hr * 190 + wcol) * 64 + ch;
#pragma unroll
      for (int q = 0; q < 8; ++q) {
        bf16x4 o;
#pragma unroll
        for (int e = 0; e < 4; ++e) o[e] = (__bf16)v[q][e];
        *(bf16x4*)(dp + q * 4) = o;
      }
    }
    __builtin_amdgcn_s_waitcnt(0);
  }
}

// ---------------- conv2 (pad 2) + residual: 1-wave block, tile 2r x 32c, y bf16 ----------------
template <bool LAST>
__global__ __launch_bounds__(64, 1) void conv2_mfma(
    const __bf16* __restrict__ hbuf, const __bf16* __restrict__ w2A,
    const float* __restrict__ xlow, __bf16* __restrict__ y,
    float* __restrict__ out) {
  __shared__ __align__(16) unsigned char smem[LDSB];
  int b = blockIdx.x / 576, r = blockIdx.x % 576, rt = r / 6, ct = r % 6;
  int h0 = rt * 2, w0 = ct * 32;
  int lane = threadIdx.x & 63;
  int m = lane & 31, kh8 = (lane >> 5) << 3;
  int colb = m, ch = (lane >> 5) * 32;
  const unsigned char* bB = smem + m * TCS + kh8 * 2;
  f32x16 acc[2][2];
  acc[0][0] = zero16(); acc[0][1] = zero16(); acc[1][0] = zero16(); acc[1][1] = zero16();
  stage_bf16T<6, 36, 64>(hbuf + (size_t)b * HW1 * 64, 190, 190, h0 - 2, w0 - 2, smem);
  __builtin_amdgcn_s_waitcnt(0);
  kloopT<4, 0, RPB>(w2A, bB, acc);
  __builtin_amdgcn_s_waitcnt(0);
  unsigned char* reg = smem;
#pragma unroll
  for (int pt = 0; pt < 2; ++pt) {
    acchalf_to_lds(acc, pt, reg);
    __builtin_amdgcn_s_waitcnt(0);
    f32x4 v[8];
    read_half(reg, v);
    int row = h0 + pt;
    size_t pix = (size_t)b * HW + (size_t)row * 192 + w0 + colb;
    __bf16* yp = y + pix * 64 + ch;
#pragma unroll
    for (int q = 0; q < 8; ++q) {
      bf16x4 yv = *(const bf16x4*)(yp + q * 4);
#pragma unroll
      for (int e = 0; e < 4; ++e) v[q][e] += (float)yv[e];
    }
    if (!LAST) {
#pragma unroll
      for (int q = 0; q < 8; ++q) {
        bf16x4 o;
#pragma unroll
        for (int e = 0; e < 4; ++e) o[e] = (__bf16)v[q][e];
        *(bf16x4*)(yp + q * 4) = o;
      }
    } else {
      const float* xp = xlow + pix * 64 + ch;
#pragma unroll
      for (int q = 0; q < 8; ++q) v[q] += *(const f32x4*)(xp + q * 4);
#pragma unroll
      for (int q = 0; q < 8; ++q)
        *(f32x4*)(reg + (colb * 68 + ch + q * 4) * 4) = v[q];
      __builtin_amdgcn_s_waitcnt(0);
      int o = lane;
      float* op = out + ((size_t)b * 64 + o) * HW + (size_t)row * 192 + w0;
#pragma unroll
      for (int q = 0; q < 8; ++q) {
        f32x4 s;
#pragma unroll
        for (int e = 0; e < 4; ++e)
          s[e] = *(const float*)(reg + ((q * 4 + e) * 68 + o) * 4);
        *(f32x4*)(op + q * 4) = s;
      }
    }
    __builtin_amdgcn_s_waitcnt(0);
  }
}

extern "C" void kernel_launch(void* const* d_in, const int* in_sizes, int n_in,
                              void* d_out, int out_size, void* d_ws, size_t ws_size,
                              hipStream_t stream) {
  const float* f_r      = (const float*)d_in[0];
  const float* m_t      = (const float*)d_in[1];
  const float* w_pconv  = (const float*)d_in[2];
  const float* b_pconv  = (const float*)d_in[3];
  const float* w_dc     = (const float*)d_in[4];
  const float* w_cat    = (const float*)d_in[5];
  const float* b_cat    = (const float*)d_in[6];
  const float* rb_w1    = (const float*)d_in[7];
  const float* rb_w2    = (const float*)d_in[8];
  const float* rb_beta  = (const float*)d_in[9];
  const float* rb_gamma = (const float*)d_in[10];
  float* out = (float*)d_out;

  float* ws = (float*)d_ws;
  float*  xlow  = ws;                         // [2][HW][64] f32 (residual x)
  __bf16* ybuf  = (__bf16*)(xlow + 4718592);  // [2][HW][64] bf16 (region oversized)
  float*  off20 = xlow + 4718592 + 4718592;   // [2][HW][20] f32
  __bf16* frn   = (__bf16*)(off20 + 1474560); // [2][HW][64] bf16
  __bf16* mtn   = (__bf16*)(off20 + 1474560 + 2359296);
  __bf16* hbuf  = mtn;                        // mtn dead after pconv
  float*  wbase = off20 + 1474560 + 2359296 + 2359296;
  __bf16* wpA   = (__bf16*)wbase;
  __bf16* wdcA  = (__bf16*)(wbase + 9216);
  __bf16* wcatA = (__bf16*)(wbase + 27648);
  __bf16* w1A   = (__bf16*)(wbase + 64512);
  __bf16* w2A   = (__bf16*)(wbase + 119808);
  __bf16* gA    = (__bf16*)(wbase + 175104);
  float*  bpad  = wbase + 181248;

  prep_weights<<<1417, 256, 0, stream>>>(w_pconv, b_pconv, w_dc, w_cat, rb_w1, rb_w2,
                                         rb_gamma, wpA, wdcA, wcatA, w1A, w2A, gA, bpad);
  to_nhwc_bf16<<<2304, 256, 0, stream>>>(f_r, m_t, frn, mtn);
  pconv_mfma<<<288, 256, 0, stream>>>(mtn, wpA, bpad, off20);
  deform_mfma<<<1152, 128, 0, stream>>>(frn, off20, wdcA, xlow);
  convcat_mfma<<<1152, 64, 0, stream>>>(xlow, frn, wcatA, b_cat, ybuf);
  for (int l = 0; l < 3; ++l) {
    conv1gdn_mfma<<<1152, 64, 0, stream>>>(ybuf, w1A + l * 36864, gA + l * 4096,
                                           rb_beta + l * 64, hbuf);
    if (l < 2)
      conv2_mfma<false><<<1152, 64, 0, stream>>>(hbuf, w2A + l * 36864, xlow, ybuf, out);
    else
      conv2_mfma<true><<<1152, 64, 0, stream>>>(hbuf, w2A + l * 36864, xlow, ybuf, out);
  }
}